// Round 11
// baseline (107.067 us; speedup 1.0000x reference)
//
#include <hip/hip_runtime.h>
#include <hip/hip_bf16.h>
#include <hip/hip_fp16.h>

#define N_G   2048
#define IMGF  128.0f
#define RECF  8          // floats per gaussian record (2 x float4, 32 B)

// record layout (8 floats):
//  [0]=mu_x [1]=mu_y [2]=A2 [3]=B2 [4]=D2 [5]=L
//  [6]=bf16pack(cr|cg<<16) [7]=bf16pack(cb)
// p2 = A2*dx^2 + B2*dx*dy + D2*dy^2 + L ; alpha = min(exp2(p2), 0.99)
// L = log2(opacity) or -1e10 if invalid (exp2 -> 0 reproduces valid-mask)
//
// Sorted storage is ITERATION-MAJOR: rank r lives at slot (r&31)*64 + (r>>5):
// at inner step i the wave's 64 lanes touch 64 adjacent records while lane l
// owns the contiguous rank range [32l, 32l+32) (scan order).
//
// Raster stages all 64 KB of records in LDS with an XOR swizzle
// (addr ^= ((slot&7)<<4)) so the stride-32B per-lane reads spread across all
// 32 banks (<=2-way aliasing = free).
//
// Sort key: u64 = mono32(depth) << 32 | idx -> stable argsort, 1 u64 compare.

typedef __fp16 half2_v __attribute__((ext_vector_type(2)));
union H2U { half2_v h2; float f; unsigned int u; };

static __device__ __forceinline__ unsigned int f32_bf16(float f) {
    unsigned int u = __float_as_uint(f);
    return (u + 0x7FFFu + ((u >> 16) & 1u)) >> 16;      // RNE, finite inputs
}

__global__ void gs_preprocess(const float* __restrict__ means,
                              const float* __restrict__ log_scales,
                              const float* __restrict__ rotations,
                              const float* __restrict__ opacity_logit,
                              const float* __restrict__ color_pre,
                              const float* __restrict__ cam_pos,
                              const float* __restrict__ look_at,
                              float* __restrict__ rec,
                              unsigned long long* __restrict__ keys)
{
    int i = blockIdx.x * blockDim.x + threadIdx.x;
    if (i >= N_G) return;

    float cx = cam_pos[0], cy = cam_pos[1], cz = cam_pos[2];
    float fx = look_at[0] - cx, fy = look_at[1] - cy, fz = look_at[2] - cz;
    float fn = 1.0f / sqrtf(fx*fx + fy*fy + fz*fz);
    fx *= fn; fy *= fn; fz *= fn;
    float rx = -fz, ry = 0.0f, rz = fx;                 // cross(fwd,(0,1,0))
    float rn = 1.0f / sqrtf(rx*rx + ry*ry + rz*rz);
    rx *= rn; ry *= rn; rz *= rn;
    float ux = ry*fz - rz*fy, uy = rz*fx - rx*fz, uz = rx*fy - ry*fx;

    float mx = means[3*i+0] - cx, my = means[3*i+1] - cy, mz = means[3*i+2] - cz;
    float m0 =  rx*mx + ry*my + rz*mz;
    float m1 =  ux*mx + uy*my + uz*mz;
    float m2 = -(fx*mx + fy*my + fz*mz);
    float d  = -m2;
    float invz = 1.0f / (-m2 + 1e-8f);
    float m2dx =  (m0 * invz) * IMGF + IMGF * 0.5f;
    float m2dy = -(m1 * invz) * IMGF + IMGF * 0.5f;

    float s0 = expf(log_scales[3*i+0]);
    float s1 = expf(log_scales[3*i+1]);
    float s2 = expf(log_scales[3*i+2]);
    float qw = rotations[4*i+0], qx = rotations[4*i+1],
          qy = rotations[4*i+2], qz = rotations[4*i+3];
    float qn = 1.0f / sqrtf(qw*qw + qx*qx + qy*qy + qz*qz);
    qw *= qn; qx *= qn; qy *= qn; qz *= qn;
    float R00 = 1-2*(qy*qy+qz*qz), R01 = 2*(qx*qy-qw*qz), R02 = 2*(qx*qz+qw*qy);
    float R10 = 2*(qx*qy+qw*qz), R11 = 1-2*(qx*qx+qz*qz), R12 = 2*(qy*qz-qw*qx);
    float R20 = 2*(qx*qz-qw*qy), R21 = 2*(qy*qz+qw*qx), R22 = 1-2*(qx*qx+qy*qy);
    float t0 = s0*s0, t1 = s1*s1, t2 = s2*s2;
    float C00 = R00*R00*t0 + R01*R01*t1 + R02*R02*t2;
    float C01 = R00*R10*t0 + R01*R11*t1 + R02*R12*t2;
    float C02 = R00*R20*t0 + R01*R21*t1 + R02*R22*t2;
    float C11 = R10*R10*t0 + R11*R11*t1 + R12*R12*t2;
    float C12 = R10*R20*t0 + R11*R21*t1 + R12*R22*t2;
    float C22 = R20*R20*t0 + R21*R21*t1 + R22*R22*t2;

    float v0 = C00*rx + C01*ry + C02*rz;
    float v1 = C01*rx + C11*ry + C12*rz;
    float v2 = C02*rx + C12*ry + C22*rz;
    float ca = rx*v0 + ry*v1 + rz*v2;
    float cb = ux*v0 + uy*v1 + uz*v2;
    float w0 = C00*ux + C01*uy + C02*uz;
    float w1 = C01*ux + C11*uy + C12*uz;
    float w2 = C02*ux + C12*uy + C22*uz;
    float cd = ux*w0 + uy*w1 + uz*w2;

    float z2 = fmaxf(d*d, 0.01f);
    float sc = (IMGF * IMGF) / z2;
    float a  = ca*sc + 0.3f;
    float b  = cb*sc;
    float dd = cd*sc + 0.3f;
    float det  = fmaxf(a*dd - b*b, 1e-6f);
    float idet = 1.0f / det;

    bool valid = (d > 0.1f) && (m2dx > -IMGF) && (m2dx < 2.0f*IMGF)
                            && (m2dy > -IMGF) && (m2dy < 2.0f*IMGF);

    float op = 1.0f / (1.0f + expf(-opacity_logit[i]));
    const float L2E = 1.4426950408889634f;
    float A2 = -0.5f * L2E * dd * idet;
    float B2 =          L2E * b  * idet;
    float D2 = -0.5f * L2E * a  * idet;
    float L  = valid ? log2f(op) : -1e10f;

    float cr = 1.0f / (1.0f + expf(-color_pre[3*i+0]));
    float cg = 1.0f / (1.0f + expf(-color_pre[3*i+1]));
    float cl = 1.0f / (1.0f + expf(-color_pre[3*i+2]));

    unsigned int w6 = f32_bf16(cr) | (f32_bf16(cg) << 16);
    unsigned int w7 = f32_bf16(cl);

    float4* r4 = (float4*)(rec + RECF*i);
    r4[0] = make_float4(m2dx, m2dy, A2, B2);
    r4[1] = make_float4(D2, L, __uint_as_float(w6), __uint_as_float(w7));

    unsigned int ub   = __float_as_uint(d);
    unsigned int mask = ((unsigned int)((int)ub >> 31)) | 0x80000000u;
    keys[i] = ((unsigned long long)(ub ^ mask) << 32) | (unsigned int)i;
}

// O(N^2) stable rank sort: 64 blocks x 256; 8 threads per gaussian, each
// counting a 256-key segment (seg-skewed LDS reads -> conflict-free), then
// 3-step shfl combine; 8 threads cooperatively copy the 32B record.
__global__ void __launch_bounds__(256)
gs_rank_scatter(const unsigned long long* __restrict__ keys,
                const float* __restrict__ rec,
                float* __restrict__ srec)
{
    __shared__ __align__(16) unsigned long long sk[N_G];
    int t = threadIdx.x;

    const ulonglong2* k2 = (const ulonglong2*)keys;
    ulonglong2* s2 = (ulonglong2*)sk;
    #pragma unroll
    for (int q = 0; q < 4; ++q) s2[t + q*256] = k2[t + q*256];   // 16 KB
    __syncthreads();

    int g   = (blockIdx.x << 5) | (t >> 3);       // 32 gaussians per block
    int seg = t & 7;                              // 8 segments x 256 keys
    unsigned long long ki = sk[g];
    const ulonglong2* sseg = (const ulonglong2*)(sk + (seg << 8));
    int rank = 0;
    #pragma unroll 8
    for (int j = 0; j < 128; ++j) {
        ulonglong2 a = sseg[(j + seg * 17) & 127];   // skew: distinct banks
        rank += (int)(a.x < ki) + (int)(a.y < ki);
    }
    rank += __shfl_xor(rank, 1);
    rank += __shfl_xor(rank, 2);
    rank += __shfl_xor(rank, 4);

    int slot = ((rank & 31) << 6) | (rank >> 5);
    srec[slot * RECF + seg] = rec[g * RECF + seg];
}

// Scan-form compositing:
//   u_k = T_{k-1} * alpha_k,  T = prefix-prod(1-alpha)
//   I   = PI_k (1-u_k) + SUM_k u_k c_k PI_{j>k} (1-u_j)
// One wave = 2 adjacent pixels; lane l owns ranks [32l, 32l+32).
// All records staged in 64 KB swizzled LDS (2 blocks/CU); no global loads in
// the hot loops. No min-wave force (round 9: forced occupancy -> 80 MB spill).
__global__ void __launch_bounds__(256)
gs_raster(const float* __restrict__ srec, float* __restrict__ out)
{
    __shared__ __align__(16) unsigned char sbuf[65536];
    int tid  = threadIdx.x;
    int lane = tid & 63;

    // ---- stage all 2048 records (4096 float4) with XOR swizzle ----
    {
        const float4* g = (const float4*)srec;
        #pragma unroll
        for (int q = tid; q < 4096; q += 256) {
            unsigned int byte = (unsigned int)q << 4;
            unsigned int swz  = byte ^ (((byte >> 5) & 7u) << 4);
            *(float4*)(sbuf + swz) = g[q];
        }
    }
    __syncthreads();

    int wave = (blockIdx.x << 2) | (tid >> 6);    // 0..8191
    int p0   = wave * 2;                          // two pixels, same row
    float px0 = (float)(p0 & 127);
    float px1 = px0 + 1.0f;
    float py  = (float)(p0 >> 7);

    unsigned int xorv  = ((unsigned int)(lane & 7)) << 4;
    unsigned int lbase = (((unsigned int)lane) << 5) ^ xorv;   // swizzled lane base

    float vp[32];                                 // f16x2-packed (u0,u1)
    float P0 = 1.0f, P1 = 1.0f;

    // ---- pass 1: alphas + lane-local prefix products ----
    #pragma unroll
    for (int i = 0; i < 32; ++i) {
        unsigned int a0 = (unsigned int)(i << 11) + lbase;     // i*2048 bits don't overlap swz bits? (i<<11 bits >=11; lbase bits <=10) -> OK as add
        float4 ra = *(const float4*)(sbuf + a0);               // mux,muy,A2,B2
        float2 rb = *(const float2*)(sbuf + (a0 ^ 16u));       // D2,L
        float dy   = py - ra.y;
        float b2dy = ra.w * dy;
        float t2   = fmaf(rb.x * dy, dy, rb.y);
        float dx0  = px0 - ra.x;
        float dx1  = px1 - ra.x;
        float q0 = fmaf(dx0, fmaf(ra.z, dx0, b2dy), t2);
        float q1 = fmaf(dx1, fmaf(ra.z, dx1, b2dy), t2);
        float a0f = fminf(__builtin_amdgcn_exp2f(q0), 0.99f);
        float a1f = fminf(__builtin_amdgcn_exp2f(q1), 0.99f);
        float u0 = P0 * a0f;  P0 *= (1.0f - a0f);
        float u1 = P1 * a1f;  P1 *= (1.0f - a1f);
        H2U hp; hp.h2 = __builtin_amdgcn_cvt_pkrtz(u0, u1);
        vp[i] = hp.f;
    }

    // ---- wave exclusive prefix product of lane totals -> T_in per lane ----
    float sp0 = P0, sp1 = P1;
    #pragma unroll
    for (int d = 1; d < 64; d <<= 1) {
        float y0 = __shfl_up(sp0, d);
        float y1 = __shfl_up(sp1, d);
        if (lane >= d) { sp0 *= y0; sp1 *= y1; }
    }
    float e0 = __shfl_up(sp0, 1);
    float e1 = __shfl_up(sp1, 1);
    float Tin0 = (lane == 0) ? 1.0f : e0;
    float Tin1 = (lane == 0) ? 1.0f : e1;

    // ---- pass 2a: lane-local product of (1-u) ----
    float B0 = 1.0f, B1 = 1.0f;
    #pragma unroll
    for (int i = 0; i < 32; ++i) {
        H2U h; h.f = vp[i];
        B0 *= fmaf(-Tin0, (float)h.h2.x, 1.0f);
        B1 *= fmaf(-Tin1, (float)h.h2.y, 1.0f);
    }

    // ---- wave exclusive suffix product -> S_out per lane ----
    float ss0 = B0, ss1 = B1;
    #pragma unroll
    for (int d = 1; d < 64; d <<= 1) {
        float y0 = __shfl_down(ss0, d);
        float y1 = __shfl_down(ss1, d);
        if (lane + d < 64) { ss0 *= y0; ss1 *= y1; }
    }
    float f0 = __shfl_down(ss0, 1);
    float f1 = __shfl_down(ss1, 1);
    float S0 = (lane == 63) ? 1.0f : f0;
    float S1 = (lane == 63) ? 1.0f : f1;

    // ---- pass 2b: descending accumulate  SUM u*c*S ----
    float ar0 = 0.0f, ag0 = 0.0f, ab0 = 0.0f;
    float ar1 = 0.0f, ag1 = 0.0f, ab1 = 0.0f;
    #pragma unroll
    for (int i = 31; i >= 0; --i) {
        unsigned int a0 = (unsigned int)(i << 11) + lbase;
        float2 cp = *(const float2*)(sbuf + (a0 ^ 16u) + 8u);  // colors
        unsigned int w6 = __float_as_uint(cp.x);
        unsigned int w7 = __float_as_uint(cp.y);
        float cr = __uint_as_float(w6 << 16);          // bf16 -> f32: 1 shl
        float cg = __uint_as_float(w6 & 0xFFFF0000u);
        float cb = __uint_as_float(w7 << 16);
        H2U h; h.f = vp[i];
        float u0  = Tin0 * (float)h.h2.x;
        float us0 = u0 * S0;
        ar0 = fmaf(us0, cr, ar0); ag0 = fmaf(us0, cg, ag0); ab0 = fmaf(us0, cb, ab0);
        S0 = fmaf(-u0, S0, S0);
        float u1  = Tin1 * (float)h.h2.y;
        float us1 = u1 * S1;
        ar1 = fmaf(us1, cr, ar1); ag1 = fmaf(us1, cg, ag1); ab1 = fmaf(us1, cb, ab1);
        S1 = fmaf(-u1, S1, S1);
    }
    // lane 0's S is now the GLOBAL product PI(1-u) = background coefficient

    // ---- wave sum-reduce the accumulators ----
    #pragma unroll
    for (int d = 1; d < 64; d <<= 1) {
        ar0 += __shfl_xor(ar0, d); ag0 += __shfl_xor(ag0, d); ab0 += __shfl_xor(ab0, d);
        ar1 += __shfl_xor(ar1, d); ag1 += __shfl_xor(ag1, d); ab1 += __shfl_xor(ab1, d);
    }

    if (lane == 0) {
        float* o0 = out + (size_t)p0 * 3;
        o0[0] = fminf(fmaxf(S0 + ar0, 0.0f), 1.0f);
        o0[1] = fminf(fmaxf(S0 + ag0, 0.0f), 1.0f);
        o0[2] = fminf(fmaxf(S0 + ab0, 0.0f), 1.0f);
        o0[3] = fminf(fmaxf(S1 + ar1, 0.0f), 1.0f);
        o0[4] = fminf(fmaxf(S1 + ag1, 0.0f), 1.0f);
        o0[5] = fminf(fmaxf(S1 + ab1, 0.0f), 1.0f);
    }
}

extern "C" void kernel_launch(void* const* d_in, const int* in_sizes, int n_in,
                              void* d_out, int out_size, void* d_ws, size_t ws_size,
                              hipStream_t stream)
{
    const float* means         = (const float*)d_in[0];
    const float* log_scales    = (const float*)d_in[1];
    const float* rotations     = (const float*)d_in[2];
    const float* opacity_logit = (const float*)d_in[3];
    const float* color_pre     = (const float*)d_in[4];
    const float* cam_pos       = (const float*)d_in[5];
    const float* look_at       = (const float*)d_in[6];
    float* out = (float*)d_out;

    char* ws = (char*)d_ws;
    float*              rec  = (float*)(ws);                         // 64 KB
    unsigned long long* keys = (unsigned long long*)(ws + 65536);    // 16 KB
    float*              srec = (float*)(ws + 65536 + 16384);         // 64 KB

    hipLaunchKernelGGL(gs_preprocess, dim3(N_G / 256), dim3(256), 0, stream,
                       means, log_scales, rotations, opacity_logit, color_pre,
                       cam_pos, look_at, rec, keys);
    hipLaunchKernelGGL(gs_rank_scatter, dim3(N_G / 32), dim3(256), 0, stream,
                       keys, rec, srec);
    // 16384 px / 2 px-per-wave = 8192 waves; 4 waves/block -> 2048 blocks
    hipLaunchKernelGGL(gs_raster, dim3(2048), dim3(256), 0, stream,
                       srec, out);
}

// Round 13
// 100.739 us; speedup vs baseline: 1.0628x; 1.0628x over previous
//
#include <hip/hip_runtime.h>
#include <hip/hip_bf16.h>
#include <hip/hip_fp16.h>

#define N_G   2048
#define IMGF  128.0f
#define RECF  8          // floats per gaussian record (2 x float4, 32 B)

// record layout (8 floats):
//  [0]=mu_x [1]=mu_y [2]=A2 [3]=B2 [4]=D2 [5]=L
//  [6]=bf16pack(cr|cg<<16) [7]=bf16pack(cb)
// p2 = A2*dx^2 + B2*dx*dy + D2*dy^2 + L ; alpha = min(exp2(p2), 0.99)
// L = log2(opacity) or -1e10 if invalid (exp2 -> 0 reproduces valid-mask)
//
// Sorted storage is ITERATION-MAJOR: rank r lives at slot (r&31)*64 + (r>>5):
// at inner step i the wave's 64 lanes touch 64 adjacent records while lane l
// owns the contiguous rank range [32l, 32l+32) (scan order).
//
// Raster: records from global (L2-resident); per-lane u-values in LDS
// (32 KB/block -> 5 blocks/CU = 5 waves/SIMD, vs 2 with 64 KB staging);
// partial unroll 8 caps VGPR so occupancy, not ILP, hides latency.
//
// Sort key: u64 = mono32(depth) << 32 | idx -> stable argsort, 1 u64 compare.

typedef __fp16 half2_v __attribute__((ext_vector_type(2)));
union H2U { half2_v h2; float f; unsigned int u; };

static __device__ __forceinline__ unsigned int f32_bf16(float f) {
    unsigned int u = __float_as_uint(f);
    return (u + 0x7FFFu + ((u >> 16) & 1u)) >> 16;      // RNE, finite inputs
}

__global__ void gs_preprocess(const float* __restrict__ means,
                              const float* __restrict__ log_scales,
                              const float* __restrict__ rotations,
                              const float* __restrict__ opacity_logit,
                              const float* __restrict__ color_pre,
                              const float* __restrict__ cam_pos,
                              const float* __restrict__ look_at,
                              float* __restrict__ rec,
                              unsigned long long* __restrict__ keys)
{
    int i = blockIdx.x * blockDim.x + threadIdx.x;
    if (i >= N_G) return;

    float cx = cam_pos[0], cy = cam_pos[1], cz = cam_pos[2];
    float fx = look_at[0] - cx, fy = look_at[1] - cy, fz = look_at[2] - cz;
    float fn = 1.0f / sqrtf(fx*fx + fy*fy + fz*fz);
    fx *= fn; fy *= fn; fz *= fn;
    float rx = -fz, ry = 0.0f, rz = fx;                 // cross(fwd,(0,1,0))
    float rn = 1.0f / sqrtf(rx*rx + ry*ry + rz*rz);
    rx *= rn; ry *= rn; rz *= rn;
    float ux = ry*fz - rz*fy, uy = rz*fx - rx*fz, uz = rx*fy - ry*fx;

    float mx = means[3*i+0] - cx, my = means[3*i+1] - cy, mz = means[3*i+2] - cz;
    float m0 =  rx*mx + ry*my + rz*mz;
    float m1 =  ux*mx + uy*my + uz*mz;
    float m2 = -(fx*mx + fy*my + fz*mz);
    float d  = -m2;
    float invz = 1.0f / (-m2 + 1e-8f);
    float m2dx =  (m0 * invz) * IMGF + IMGF * 0.5f;
    float m2dy = -(m1 * invz) * IMGF + IMGF * 0.5f;

    float s0 = expf(log_scales[3*i+0]);
    float s1 = expf(log_scales[3*i+1]);
    float s2 = expf(log_scales[3*i+2]);
    float qw = rotations[4*i+0], qx = rotations[4*i+1],
          qy = rotations[4*i+2], qz = rotations[4*i+3];
    float qn = 1.0f / sqrtf(qw*qw + qx*qx + qy*qy + qz*qz);
    qw *= qn; qx *= qn; qy *= qn; qz *= qn;
    float R00 = 1-2*(qy*qy+qz*qz), R01 = 2*(qx*qy-qw*qz), R02 = 2*(qx*qz+qw*qy);
    float R10 = 2*(qx*qy+qw*qz), R11 = 1-2*(qx*qx+qz*qz), R12 = 2*(qy*qz-qw*qx);
    float R20 = 2*(qx*qz-qw*qy), R21 = 2*(qy*qz+qw*qx), R22 = 1-2*(qx*qx+qy*qy);
    float t0 = s0*s0, t1 = s1*s1, t2 = s2*s2;
    float C00 = R00*R00*t0 + R01*R01*t1 + R02*R02*t2;
    float C01 = R00*R10*t0 + R01*R11*t1 + R02*R12*t2;
    float C02 = R00*R20*t0 + R01*R21*t1 + R02*R22*t2;
    float C11 = R10*R10*t0 + R11*R11*t1 + R12*R12*t2;
    float C12 = R10*R20*t0 + R11*R21*t1 + R12*R22*t2;
    float C22 = R20*R20*t0 + R21*R21*t1 + R22*R22*t2;

    float v0 = C00*rx + C01*ry + C02*rz;
    float v1 = C01*rx + C11*ry + C12*rz;
    float v2 = C02*rx + C12*ry + C22*rz;
    float ca = rx*v0 + ry*v1 + rz*v2;
    float cb = ux*v0 + uy*v1 + uz*v2;
    float w0 = C00*ux + C01*uy + C02*uz;
    float w1 = C01*ux + C11*uy + C12*uz;
    float w2 = C02*ux + C12*uy + C22*uz;
    float cd = ux*w0 + uy*w1 + uz*w2;

    float z2 = fmaxf(d*d, 0.01f);
    float sc = (IMGF * IMGF) / z2;
    float a  = ca*sc + 0.3f;
    float b  = cb*sc;
    float dd = cd*sc + 0.3f;
    float det  = fmaxf(a*dd - b*b, 1e-6f);
    float idet = 1.0f / det;

    bool valid = (d > 0.1f) && (m2dx > -IMGF) && (m2dx < 2.0f*IMGF)
                            && (m2dy > -IMGF) && (m2dy < 2.0f*IMGF);

    float op = 1.0f / (1.0f + expf(-opacity_logit[i]));
    const float L2E = 1.4426950408889634f;
    float A2 = -0.5f * L2E * dd * idet;
    float B2 =          L2E * b  * idet;
    float D2 = -0.5f * L2E * a  * idet;
    float L  = valid ? log2f(op) : -1e10f;

    float cr = 1.0f / (1.0f + expf(-color_pre[3*i+0]));
    float cg = 1.0f / (1.0f + expf(-color_pre[3*i+1]));
    float cl = 1.0f / (1.0f + expf(-color_pre[3*i+2]));

    unsigned int w6 = f32_bf16(cr) | (f32_bf16(cg) << 16);
    unsigned int w7 = f32_bf16(cl);

    float4* r4 = (float4*)(rec + RECF*i);
    r4[0] = make_float4(m2dx, m2dy, A2, B2);
    r4[1] = make_float4(D2, L, __uint_as_float(w6), __uint_as_float(w7));

    unsigned int ub   = __float_as_uint(d);
    unsigned int mask = ((unsigned int)((int)ub >> 31)) | 0x80000000u;
    keys[i] = ((unsigned long long)(ub ^ mask) << 32) | (unsigned int)i;
}

// O(N^2) stable rank sort: 64 blocks x 256; 8 threads per gaussian, each
// counting a 256-key segment (seg-skewed LDS reads -> conflict-free), then
// 3-step shfl combine; 8 threads cooperatively copy the 32B record.
__global__ void __launch_bounds__(256)
gs_rank_scatter(const unsigned long long* __restrict__ keys,
                const float* __restrict__ rec,
                float* __restrict__ srec)
{
    __shared__ __align__(16) unsigned long long sk[N_G];
    int t = threadIdx.x;

    const ulonglong2* k2 = (const ulonglong2*)keys;
    ulonglong2* s2 = (ulonglong2*)sk;
    #pragma unroll
    for (int q = 0; q < 4; ++q) s2[t + q*256] = k2[t + q*256];   // 16 KB
    __syncthreads();

    int g   = (blockIdx.x << 5) | (t >> 3);       // 32 gaussians per block
    int seg = t & 7;                              // 8 segments x 256 keys
    unsigned long long ki = sk[g];
    const ulonglong2* sseg = (const ulonglong2*)(sk + (seg << 8));
    int rank = 0;
    #pragma unroll 8
    for (int j = 0; j < 128; ++j) {
        ulonglong2 a = sseg[(j + seg * 17) & 127];   // skew: distinct banks
        rank += (int)(a.x < ki) + (int)(a.y < ki);
    }
    rank += __shfl_xor(rank, 1);
    rank += __shfl_xor(rank, 2);
    rank += __shfl_xor(rank, 4);

    int slot = ((rank & 31) << 6) | (rank >> 5);
    srec[slot * RECF + seg] = rec[g * RECF + seg];
}

// Scan-form compositing:
//   u_k = T_{k-1} * alpha_k,  T = prefix-prod(1-alpha)
//   I   = PI_k (1-u_k) + SUM_k u_k c_k PI_{j>k} (1-u_j)
// One wave = 2 adjacent pixels; lane l owns ranks [32l, 32l+32).
// u-values live in LDS (32 KB/block -> 5 blocks/CU); records read from
// global/L2; unroll 8 keeps VGPR low so occupancy hides latency.
__global__ void __launch_bounds__(256)
gs_raster(const float* __restrict__ srec, float* __restrict__ out)
{
    __shared__ float vp_lds[4 * 32 * 64];         // [wid][i][lane] -> 32 KB
    int tid  = threadIdx.x;
    int lane = tid & 63;
    int wid  = tid >> 6;
    int vbase = (wid << 11) | lane;               // + (i<<6)

    int wave = (blockIdx.x << 2) | wid;           // 0..8191
    int p0   = wave * 2;                          // two pixels, same row
    float px0 = (float)(p0 & 127);
    float px1 = px0 + 1.0f;
    float py  = (float)(p0 >> 7);

    float P0 = 1.0f, P1 = 1.0f;

    // ---- pass 1: alphas + lane-local prefix products (u -> LDS) ----
    #pragma unroll 8
    for (int i = 0; i < 32; ++i) {
        const float* r = srec + (size_t)((i << 6) | lane) * RECF;
        float4 ra = *(const float4*)r;            // mux,muy,A2,B2
        float2 rb = *(const float2*)(r + 4);      // D2,L
        float dy   = py - ra.y;
        float b2dy = ra.w * dy;
        float t2   = fmaf(rb.x * dy, dy, rb.y);
        float dx0  = px0 - ra.x;
        float dx1  = px1 - ra.x;
        float q0 = fmaf(dx0, fmaf(ra.z, dx0, b2dy), t2);
        float q1 = fmaf(dx1, fmaf(ra.z, dx1, b2dy), t2);
        float a0 = fminf(__builtin_amdgcn_exp2f(q0), 0.99f);
        float a1 = fminf(__builtin_amdgcn_exp2f(q1), 0.99f);
        float u0 = P0 * a0;  P0 *= (1.0f - a0);
        float u1 = P1 * a1;  P1 *= (1.0f - a1);
        H2U hp; hp.h2 = __builtin_amdgcn_cvt_pkrtz(u0, u1);
        vp_lds[vbase | (i << 6)] = hp.f;
    }

    // ---- wave exclusive prefix product of lane totals -> T_in per lane ----
    float sp0 = P0, sp1 = P1;
    #pragma unroll
    for (int d = 1; d < 64; d <<= 1) {
        float y0 = __shfl_up(sp0, d);
        float y1 = __shfl_up(sp1, d);
        if (lane >= d) { sp0 *= y0; sp1 *= y1; }
    }
    float e0 = __shfl_up(sp0, 1);
    float e1 = __shfl_up(sp1, 1);
    float Tin0 = (lane == 0) ? 1.0f : e0;
    float Tin1 = (lane == 0) ? 1.0f : e1;

    // ---- pass 2a: lane-local product of (1-u) ----
    float B0 = 1.0f, B1 = 1.0f;
    #pragma unroll 8
    for (int i = 0; i < 32; ++i) {
        H2U h; h.f = vp_lds[vbase | (i << 6)];
        B0 *= fmaf(-Tin0, (float)h.h2.x, 1.0f);
        B1 *= fmaf(-Tin1, (float)h.h2.y, 1.0f);
    }

    // ---- wave exclusive suffix product -> S_out per lane ----
    float ss0 = B0, ss1 = B1;
    #pragma unroll
    for (int d = 1; d < 64; d <<= 1) {
        float y0 = __shfl_down(ss0, d);
        float y1 = __shfl_down(ss1, d);
        if (lane + d < 64) { ss0 *= y0; ss1 *= y1; }
    }
    float f0 = __shfl_down(ss0, 1);
    float f1 = __shfl_down(ss1, 1);
    float S0 = (lane == 63) ? 1.0f : f0;
    float S1 = (lane == 63) ? 1.0f : f1;

    // ---- pass 2b: descending accumulate  SUM u*c*S ----
    float ar0 = 0.0f, ag0 = 0.0f, ab0 = 0.0f;
    float ar1 = 0.0f, ag1 = 0.0f, ab1 = 0.0f;
    #pragma unroll 8
    for (int i = 31; i >= 0; --i) {
        const float* r = srec + (size_t)((i << 6) | lane) * RECF;
        float2 cp = *(const float2*)(r + 6);
        unsigned int w6 = __float_as_uint(cp.x);
        unsigned int w7 = __float_as_uint(cp.y);
        float cr = __uint_as_float(w6 << 16);          // bf16 -> f32: 1 shl
        float cg = __uint_as_float(w6 & 0xFFFF0000u);
        float cb = __uint_as_float(w7 << 16);
        H2U h; h.f = vp_lds[vbase | (i << 6)];
        float u0  = Tin0 * (float)h.h2.x;
        float us0 = u0 * S0;
        ar0 = fmaf(us0, cr, ar0); ag0 = fmaf(us0, cg, ag0); ab0 = fmaf(us0, cb, ab0);
        S0 = fmaf(-u0, S0, S0);
        float u1  = Tin1 * (float)h.h2.y;
        float us1 = u1 * S1;
        ar1 = fmaf(us1, cr, ar1); ag1 = fmaf(us1, cg, ab1*0.0f + ag1), ab1 = fmaf(us1, cb, ab1);
        S1 = fmaf(-u1, S1, S1);
    }
    // lane 0's S is now the GLOBAL product PI(1-u) = background coefficient

    // ---- wave sum-reduce the accumulators ----
    #pragma unroll
    for (int d = 1; d < 64; d <<= 1) {
        ar0 += __shfl_xor(ar0, d); ag0 += __shfl_xor(ag0, d); ab0 += __shfl_xor(ab0, d);
        ar1 += __shfl_xor(ar1, d); ag1 += __shfl_xor(ag1, d); ab1 += __shfl_xor(ab1, d);
    }

    if (lane == 0) {
        float* o0 = out + (size_t)p0 * 3;
        o0[0] = fminf(fmaxf(S0 + ar0, 0.0f), 1.0f);
        o0[1] = fminf(fmaxf(S0 + ag0, 0.0f), 1.0f);
        o0[2] = fminf(fmaxf(S0 + ab0, 0.0f), 1.0f);
        o0[3] = fminf(fmaxf(S1 + ar1, 0.0f), 1.0f);
        o0[4] = fminf(fmaxf(S1 + ag1, 0.0f), 1.0f);
        o0[5] = fminf(fmaxf(S1 + ab1, 0.0f), 1.0f);
    }
}

extern "C" void kernel_launch(void* const* d_in, const int* in_sizes, int n_in,
                              void* d_out, int out_size, void* d_ws, size_t ws_size,
                              hipStream_t stream)
{
    const float* means         = (const float*)d_in[0];
    const float* log_scales    = (const float*)d_in[1];
    const float* rotations     = (const float*)d_in[2];
    const float* opacity_logit = (const float*)d_in[3];
    const float* color_pre     = (const float*)d_in[4];
    const float* cam_pos       = (const float*)d_in[5];
    const float* look_at       = (const float*)d_in[6];
    float* out = (float*)d_out;

    char* ws = (char*)d_ws;
    float*              rec  = (float*)(ws);                         // 64 KB
    unsigned long long* keys = (unsigned long long*)(ws + 65536);    // 16 KB
    float*              srec = (float*)(ws + 65536 + 16384);         // 64 KB

    hipLaunchKernelGGL(gs_preprocess, dim3(N_G / 256), dim3(256), 0, stream,
                       means, log_scales, rotations, opacity_logit, color_pre,
                       cam_pos, look_at, rec, keys);
    hipLaunchKernelGGL(gs_rank_scatter, dim3(N_G / 32), dim3(256), 0, stream,
                       keys, rec, srec);
    // 16384 px / 2 px-per-wave = 8192 waves; 4 waves/block -> 2048 blocks
    hipLaunchKernelGGL(gs_raster, dim3(2048), dim3(256), 0, stream,
                       srec, out);
}

// Round 14
// 99.006 us; speedup vs baseline: 1.0814x; 1.0175x over previous
//
#include <hip/hip_runtime.h>
#include <hip/hip_bf16.h>
#include <hip/hip_fp16.h>

#define N_G   2048
#define IMGF  128.0f
#define RECF  8          // floats per gaussian record (2 x float4, 32 B)

// record layout (8 floats):
//  [0]=mu_x [1]=mu_y [2]=A2 [3]=B2 [4]=D2 [5]=L
//  [6]=bf16pack(cr|cg<<16) [7]=bf16pack(cb)
// p2 = A2*dx^2 + B2*dx*dy + D2*dy^2 + L ; alpha = min(exp2(p2), 0.99)
// L = log2(opacity) or -1e10 if invalid (exp2 -> 0 reproduces valid-mask)
//
// ROUND STRUCTURE: raster processes 4 sequential rounds of 512 ranks.
// Within a round, lane l owns contiguous ranks [512r+8l, 512r+8l+8), and at
// step i the 64 lanes read ranks 512r + {8l+i} stored at physical slot
// s(rank) = (rank&~511) | ((rank&7)<<6) | ((rank>>3)&63)
// -> at (r,i) lanes read 64 CONSECUTIVE slots (coalesced 2 KB). Compositing
// carries (G=prod(1-u), T=prod(1-alpha), A=deferred contribs) across rounds:
// I_out = I_in*M + C per round is exact (operator applied to subsequence).
// vp[8] fits in registers -> NO LDS, no barriers, high occupancy.
//
// Sort key: u64 = mono32(depth) << 32 | idx -> stable argsort, 1 u64 compare.

typedef __fp16 half2_v __attribute__((ext_vector_type(2)));
union H2U { half2_v h2; float f; unsigned int u; };

static __device__ __forceinline__ unsigned int f32_bf16(float f) {
    unsigned int u = __float_as_uint(f);
    return (u + 0x7FFFu + ((u >> 16) & 1u)) >> 16;      // RNE, finite inputs
}

__global__ void gs_preprocess(const float* __restrict__ means,
                              const float* __restrict__ log_scales,
                              const float* __restrict__ rotations,
                              const float* __restrict__ opacity_logit,
                              const float* __restrict__ color_pre,
                              const float* __restrict__ cam_pos,
                              const float* __restrict__ look_at,
                              float* __restrict__ rec,
                              unsigned long long* __restrict__ keys)
{
    int i = blockIdx.x * blockDim.x + threadIdx.x;
    if (i >= N_G) return;

    float cx = cam_pos[0], cy = cam_pos[1], cz = cam_pos[2];
    float fx = look_at[0] - cx, fy = look_at[1] - cy, fz = look_at[2] - cz;
    float fn = 1.0f / sqrtf(fx*fx + fy*fy + fz*fz);
    fx *= fn; fy *= fn; fz *= fn;
    float rx = -fz, ry = 0.0f, rz = fx;                 // cross(fwd,(0,1,0))
    float rn = 1.0f / sqrtf(rx*rx + ry*ry + rz*rz);
    rx *= rn; ry *= rn; rz *= rn;
    float ux = ry*fz - rz*fy, uy = rz*fx - rx*fz, uz = rx*fy - ry*fx;

    float mx = means[3*i+0] - cx, my = means[3*i+1] - cy, mz = means[3*i+2] - cz;
    float m0 =  rx*mx + ry*my + rz*mz;
    float m1 =  ux*mx + uy*my + uz*mz;
    float m2 = -(fx*mx + fy*my + fz*mz);
    float d  = -m2;
    float invz = 1.0f / (-m2 + 1e-8f);
    float m2dx =  (m0 * invz) * IMGF + IMGF * 0.5f;
    float m2dy = -(m1 * invz) * IMGF + IMGF * 0.5f;

    float s0 = expf(log_scales[3*i+0]);
    float s1 = expf(log_scales[3*i+1]);
    float s2 = expf(log_scales[3*i+2]);
    float qw = rotations[4*i+0], qx = rotations[4*i+1],
          qy = rotations[4*i+2], qz = rotations[4*i+3];
    float qn = 1.0f / sqrtf(qw*qw + qx*qx + qy*qy + qz*qz);
    qw *= qn; qx *= qn; qy *= qn; qz *= qn;
    float R00 = 1-2*(qy*qy+qz*qz), R01 = 2*(qx*qy-qw*qz), R02 = 2*(qx*qz+qw*qy);
    float R10 = 2*(qx*qy+qw*qz), R11 = 1-2*(qx*qx+qz*qz), R12 = 2*(qy*qz-qw*qx);
    float R20 = 2*(qx*qz-qw*qy), R21 = 2*(qy*qz+qw*qx), R22 = 1-2*(qx*qx+qy*qy);
    float t0 = s0*s0, t1 = s1*s1, t2 = s2*s2;
    float C00 = R00*R00*t0 + R01*R01*t1 + R02*R02*t2;
    float C01 = R00*R10*t0 + R01*R11*t1 + R02*R12*t2;
    float C02 = R00*R20*t0 + R01*R21*t1 + R02*R22*t2;
    float C11 = R10*R10*t0 + R11*R11*t1 + R12*R12*t2;
    float C12 = R10*R20*t0 + R11*R21*t1 + R12*R22*t2;
    float C22 = R20*R20*t0 + R21*R21*t1 + R22*R22*t2;

    float v0 = C00*rx + C01*ry + C02*rz;
    float v1 = C01*rx + C11*ry + C12*rz;
    float v2 = C02*rx + C12*ry + C22*rz;
    float ca = rx*v0 + ry*v1 + rz*v2;
    float cb = ux*v0 + uy*v1 + uz*v2;
    float w0 = C00*ux + C01*uy + C02*uz;
    float w1 = C01*ux + C11*uy + C12*uz;
    float w2 = C02*ux + C12*uy + C22*uz;
    float cd = ux*w0 + uy*w1 + uz*w2;

    float z2 = fmaxf(d*d, 0.01f);
    float sc = (IMGF * IMGF) / z2;
    float a  = ca*sc + 0.3f;
    float b  = cb*sc;
    float dd = cd*sc + 0.3f;
    float det  = fmaxf(a*dd - b*b, 1e-6f);
    float idet = 1.0f / det;

    bool valid = (d > 0.1f) && (m2dx > -IMGF) && (m2dx < 2.0f*IMGF)
                            && (m2dy > -IMGF) && (m2dy < 2.0f*IMGF);

    float op = 1.0f / (1.0f + expf(-opacity_logit[i]));
    const float L2E = 1.4426950408889634f;
    float A2 = -0.5f * L2E * dd * idet;
    float B2 =          L2E * b  * idet;
    float D2 = -0.5f * L2E * a  * idet;
    float L  = valid ? log2f(op) : -1e10f;

    float cr = 1.0f / (1.0f + expf(-color_pre[3*i+0]));
    float cg = 1.0f / (1.0f + expf(-color_pre[3*i+1]));
    float cl = 1.0f / (1.0f + expf(-color_pre[3*i+2]));

    unsigned int w6 = f32_bf16(cr) | (f32_bf16(cg) << 16);
    unsigned int w7 = f32_bf16(cl);

    float4* r4 = (float4*)(rec + RECF*i);
    r4[0] = make_float4(m2dx, m2dy, A2, B2);
    r4[1] = make_float4(D2, L, __uint_as_float(w6), __uint_as_float(w7));

    unsigned int ub   = __float_as_uint(d);
    unsigned int mask = ((unsigned int)((int)ub >> 31)) | 0x80000000u;
    keys[i] = ((unsigned long long)(ub ^ mask) << 32) | (unsigned int)i;
}

// O(N^2) stable rank sort: 64 blocks x 256; 8 threads per gaussian, each
// counting a 256-key segment (seg-skewed LDS reads), 3-step shfl combine;
// 8 threads cooperatively copy the 32B record to the round-major slot.
__global__ void __launch_bounds__(256)
gs_rank_scatter(const unsigned long long* __restrict__ keys,
                const float* __restrict__ rec,
                float* __restrict__ srec)
{
    __shared__ __align__(16) unsigned long long sk[N_G];
    int t = threadIdx.x;

    const ulonglong2* k2 = (const ulonglong2*)keys;
    ulonglong2* s2 = (ulonglong2*)sk;
    #pragma unroll
    for (int q = 0; q < 4; ++q) s2[t + q*256] = k2[t + q*256];   // 16 KB
    __syncthreads();

    int g   = (blockIdx.x << 5) | (t >> 3);       // 32 gaussians per block
    int seg = t & 7;                              // 8 segments x 256 keys
    unsigned long long ki = sk[g];
    const ulonglong2* sseg = (const ulonglong2*)(sk + (seg << 8));
    int rank = 0;
    #pragma unroll 8
    for (int j = 0; j < 128; ++j) {
        ulonglong2 a = sseg[(j + seg * 17) & 127];   // skew: distinct banks
        rank += (int)(a.x < ki) + (int)(a.y < ki);
    }
    rank += __shfl_xor(rank, 1);
    rank += __shfl_xor(rank, 2);
    rank += __shfl_xor(rank, 4);

    // round-major slot: round = rank>>9, step = rank&7, lane = (rank>>3)&63
    int slot = (rank & ~511) | ((rank & 7) << 6) | ((rank >> 3) & 63);
    srec[slot * RECF + seg] = rec[g * RECF + seg];
}

// Scan-form compositing in 4 sequential rounds of 512 ranks.
// Per round: lane computes 8 alphas/u-values (registers), wave prefix-product
// scan gives Tin, descending local pass gives (contrib, B), wave suffix scan
// gives S_out and M = prod(1-u); carries: G *= M, T *= prod(1-alpha),
// A = A*M + contrib*S_out.  Final: I = G + wave_sum(A) over background 1.
__global__ void __launch_bounds__(256)
gs_raster(const float* __restrict__ srec, float* __restrict__ out)
{
    int tid  = threadIdx.x;
    int lane = tid & 63;
    int wave = (blockIdx.x << 2) | (tid >> 6);    // 0..8191
    int p0   = wave * 2;                          // two pixels, same row
    float px0 = (float)(p0 & 127);
    float px1 = px0 + 1.0f;
    float py  = (float)(p0 >> 7);

    float G0 = 1.0f, G1 = 1.0f;                   // prod(1-u) so far
    float Tc0 = 1.0f, Tc1 = 1.0f;                 // prod(1-alpha) so far
    float Ar0 = 0.0f, Ag0 = 0.0f, Ab0 = 0.0f;     // deferred contributions
    float Ar1 = 0.0f, Ag1 = 0.0f, Ab1 = 0.0f;

    #pragma unroll 1
    for (int r = 0; r < 4; ++r) {
        const float* base = srec + (size_t)((r << 9) | lane) * RECF;

        // ---- local pass 1: alphas + lane prefix products ----
        float vp[8];
        float P0 = 1.0f, P1 = 1.0f;
        #pragma unroll
        for (int i = 0; i < 8; ++i) {
            const float* rp = base + (size_t)(i << 6) * RECF;
            float4 ra = *(const float4*)rp;           // mux,muy,A2,B2
            float2 rb = *(const float2*)(rp + 4);     // D2,L
            float dy   = py - ra.y;
            float b2dy = ra.w * dy;
            float t2   = fmaf(rb.x * dy, dy, rb.y);
            float dx0  = px0 - ra.x;
            float dx1  = px1 - ra.x;
            float q0 = fmaf(dx0, fmaf(ra.z, dx0, b2dy), t2);
            float q1 = fmaf(dx1, fmaf(ra.z, dx1, b2dy), t2);
            float a0 = fminf(__builtin_amdgcn_exp2f(q0), 0.99f);
            float a1 = fminf(__builtin_amdgcn_exp2f(q1), 0.99f);
            float u0 = P0 * a0;  P0 *= (1.0f - a0);
            float u1 = P1 * a1;  P1 *= (1.0f - a1);
            H2U hp; hp.h2 = __builtin_amdgcn_cvt_pkrtz(u0, u1);
            vp[i] = hp.f;
        }

        // ---- wave inclusive prefix product of P -> Tin, carry total ----
        float sp0 = P0, sp1 = P1;
        #pragma unroll
        for (int d = 1; d < 64; d <<= 1) {
            float y0 = __shfl_up(sp0, d);
            float y1 = __shfl_up(sp1, d);
            if (lane >= d) { sp0 *= y0; sp1 *= y1; }
        }
        float e0 = __shfl_up(sp0, 1);
        float e1 = __shfl_up(sp1, 1);
        float Tin0 = Tc0 * ((lane == 0) ? 1.0f : e0);
        float Tin1 = Tc1 * ((lane == 0) ? 1.0f : e1);
        float tot0 = __shfl(sp0, 63);                 // round prod(1-alpha)
        float tot1 = __shfl(sp1, 63);

        // ---- local pass 2 (descending): contrib + B = prod(1-u) ----
        float Sl0 = 1.0f, Sl1 = 1.0f;
        float cr0 = 0.0f, cg0 = 0.0f, cb0 = 0.0f;
        float cr1 = 0.0f, cg1 = 0.0f, cb1 = 0.0f;
        #pragma unroll
        for (int i = 7; i >= 0; --i) {
            const float* rp = base + (size_t)(i << 6) * RECF;
            float2 cp = *(const float2*)(rp + 6);
            unsigned int w6 = __float_as_uint(cp.x);
            unsigned int w7 = __float_as_uint(cp.y);
            float ccr = __uint_as_float(w6 << 16);    // bf16 -> f32: 1 shl
            float ccg = __uint_as_float(w6 & 0xFFFF0000u);
            float ccb = __uint_as_float(w7 << 16);
            H2U h; h.f = vp[i];
            float u0  = Tin0 * (float)h.h2.x;
            float us0 = u0 * Sl0;
            cr0 = fmaf(us0, ccr, cr0); cg0 = fmaf(us0, ccg, cg0); cb0 = fmaf(us0, ccb, cb0);
            Sl0 = fmaf(-u0, Sl0, Sl0);
            float u1  = Tin1 * (float)h.h2.y;
            float us1 = u1 * Sl1;
            cr1 = fmaf(us1, ccr, cr1); cg1 = fmaf(us1, ccg, cg1); cb1 = fmaf(us1, ccb, cb1);
            Sl1 = fmaf(-u1, Sl1, Sl1);
        }

        // ---- wave inclusive suffix product of B -> S_out, M ----
        float ss0 = Sl0, ss1 = Sl1;
        #pragma unroll
        for (int d = 1; d < 64; d <<= 1) {
            float y0 = __shfl_down(ss0, d);
            float y1 = __shfl_down(ss1, d);
            if (lane + d < 64) { ss0 *= y0; ss1 *= y1; }
        }
        float f0 = __shfl_down(ss0, 1);
        float f1 = __shfl_down(ss1, 1);
        float So0 = (lane == 63) ? 1.0f : f0;
        float So1 = (lane == 63) ? 1.0f : f1;
        float M0 = __shfl(ss0, 0);                    // round prod(1-u)
        float M1 = __shfl(ss1, 0);

        // ---- fold round into carries ----
        Ar0 = fmaf(Ar0, M0, cr0 * So0);
        Ag0 = fmaf(Ag0, M0, cg0 * So0);
        Ab0 = fmaf(Ab0, M0, cb0 * So0);
        Ar1 = fmaf(Ar1, M1, cr1 * So1);
        Ag1 = fmaf(Ag1, M1, cg1 * So1);
        Ab1 = fmaf(Ab1, M1, cb1 * So1);
        G0 *= M0;  G1 *= M1;
        Tc0 *= tot0;  Tc1 *= tot1;
    }

    // ---- wave sum-reduce the deferred contributions ----
    #pragma unroll
    for (int d = 1; d < 64; d <<= 1) {
        Ar0 += __shfl_xor(Ar0, d); Ag0 += __shfl_xor(Ag0, d); Ab0 += __shfl_xor(Ab0, d);
        Ar1 += __shfl_xor(Ar1, d); Ag1 += __shfl_xor(Ag1, d); Ab1 += __shfl_xor(Ab1, d);
    }

    if (lane == 0) {
        float* o0 = out + (size_t)p0 * 3;
        o0[0] = fminf(fmaxf(G0 + Ar0, 0.0f), 1.0f);
        o0[1] = fminf(fmaxf(G0 + Ag0, 0.0f), 1.0f);
        o0[2] = fminf(fmaxf(G0 + Ab0, 0.0f), 1.0f);
        o0[3] = fminf(fmaxf(G1 + Ar1, 0.0f), 1.0f);
        o0[4] = fminf(fmaxf(G1 + Ag1, 0.0f), 1.0f);
        o0[5] = fminf(fmaxf(G1 + Ab1, 0.0f), 1.0f);
    }
}

extern "C" void kernel_launch(void* const* d_in, const int* in_sizes, int n_in,
                              void* d_out, int out_size, void* d_ws, size_t ws_size,
                              hipStream_t stream)
{
    const float* means         = (const float*)d_in[0];
    const float* log_scales    = (const float*)d_in[1];
    const float* rotations     = (const float*)d_in[2];
    const float* opacity_logit = (const float*)d_in[3];
    const float* color_pre     = (const float*)d_in[4];
    const float* cam_pos       = (const float*)d_in[5];
    const float* look_at       = (const float*)d_in[6];
    float* out = (float*)d_out;

    char* ws = (char*)d_ws;
    float*              rec  = (float*)(ws);                         // 64 KB
    unsigned long long* keys = (unsigned long long*)(ws + 65536);    // 16 KB
    float*              srec = (float*)(ws + 65536 + 16384);         // 64 KB

    hipLaunchKernelGGL(gs_preprocess, dim3(N_G / 256), dim3(256), 0, stream,
                       means, log_scales, rotations, opacity_logit, color_pre,
                       cam_pos, look_at, rec, keys);
    hipLaunchKernelGGL(gs_rank_scatter, dim3(N_G / 32), dim3(256), 0, stream,
                       keys, rec, srec);
    // 16384 px / 2 px-per-wave = 8192 waves; 4 waves/block -> 2048 blocks
    hipLaunchKernelGGL(gs_raster, dim3(2048), dim3(256), 0, stream,
                       srec, out);
}

// Round 17
// 97.165 us; speedup vs baseline: 1.1019x; 1.0189x over previous
//
#include <hip/hip_runtime.h>
#include <hip/hip_bf16.h>
#include <hip/hip_fp16.h>

#define N_G   2048
#define IMGF  128.0f
#define RECF  8          // floats per gaussian record (2 x float4, 32 B)

// record layout (8 floats):
//  [0]=mu_x [1]=mu_y [2]=A2 [3]=B2 [4]=D2 [5]=L
//  [6]=bf16pack(cr|cg<<16) [7]=bf16pack(cb)
// p2 = A2*dx^2 + B2*dx*dy + D2*dy^2 + L ; alpha = min(exp2(p2), 0.99)
// L = log2(opacity) or -1e10 if invalid (exp2 -> 0 reproduces valid-mask)
//
// ROUND STRUCTURE: raster processes 4 sequential rounds of 512 ranks.
// Within a round, lane l owns contiguous ranks [512r+8l, 512r+8l+8); at step i
// the 64 lanes read ranks 512r + {8l+i} stored at physical slot
// s(rank) = (rank&~511) | ((rank&7)<<6) | ((rank>>3)&63)
// -> at (r,i) lanes read 64 CONSECUTIVE slots (coalesced 2 KB).
// Compositing carries (G=prod(1-u), Tc=prod(1-alpha), A=deferred contribs)
// across rounds; per-round operator I_out = I_in*M + C is exact.
// 4 PIXELS PER WAVE: record loads amortized 4x; colors kept in registers
// from pass 1 so the descending pass does zero loads.
//
// Sort key: u64 = mono32(depth) << 32 | idx -> stable argsort, 1 u64 compare.

typedef __fp16 half2_v __attribute__((ext_vector_type(2)));
union H2U { half2_v h2; float f; unsigned int u; };

static __device__ __forceinline__ unsigned int f32_bf16(float f) {
    unsigned int u = __float_as_uint(f);
    return (u + 0x7FFFu + ((u >> 16) & 1u)) >> 16;      // RNE, finite inputs
}

__global__ void gs_preprocess(const float* __restrict__ means,
                              const float* __restrict__ log_scales,
                              const float* __restrict__ rotations,
                              const float* __restrict__ opacity_logit,
                              const float* __restrict__ color_pre,
                              const float* __restrict__ cam_pos,
                              const float* __restrict__ look_at,
                              float* __restrict__ rec,
                              unsigned long long* __restrict__ keys)
{
    int i = blockIdx.x * blockDim.x + threadIdx.x;
    if (i >= N_G) return;

    float cx = cam_pos[0], cy = cam_pos[1], cz = cam_pos[2];
    float fx = look_at[0] - cx, fy = look_at[1] - cy, fz = look_at[2] - cz;
    float fn = 1.0f / sqrtf(fx*fx + fy*fy + fz*fz);
    fx *= fn; fy *= fn; fz *= fn;
    float rx = -fz, ry = 0.0f, rz = fx;                 // cross(fwd,(0,1,0))
    float rn = 1.0f / sqrtf(rx*rx + ry*ry + rz*rz);
    rx *= rn; ry *= rn; rz *= rn;
    float ux = ry*fz - rz*fy, uy = rz*fx - rx*fz, uz = rx*fy - ry*fx;

    float mx = means[3*i+0] - cx, my = means[3*i+1] - cy, mz = means[3*i+2] - cz;
    float m0 =  rx*mx + ry*my + rz*mz;
    float m1 =  ux*mx + uy*my + uz*mz;
    float m2 = -(fx*mx + fy*my + fz*mz);
    float d  = -m2;
    float invz = 1.0f / (-m2 + 1e-8f);
    float m2dx =  (m0 * invz) * IMGF + IMGF * 0.5f;
    float m2dy = -(m1 * invz) * IMGF + IMGF * 0.5f;

    float s0 = expf(log_scales[3*i+0]);
    float s1 = expf(log_scales[3*i+1]);
    float s2 = expf(log_scales[3*i+2]);
    float qw = rotations[4*i+0], qx = rotations[4*i+1],
          qy = rotations[4*i+2], qz = rotations[4*i+3];
    float qn = 1.0f / sqrtf(qw*qw + qx*qx + qy*qy + qz*qz);
    qw *= qn; qx *= qn; qy *= qn; qz *= qn;
    float R00 = 1-2*(qy*qy+qz*qz), R01 = 2*(qx*qy-qw*qz), R02 = 2*(qx*qz+qw*qy);
    float R10 = 2*(qx*qy+qw*qz), R11 = 1-2*(qx*qx+qz*qz), R12 = 2*(qy*qz-qw*qx);
    float R20 = 2*(qx*qz-qw*qy), R21 = 2*(qy*qz+qw*qx), R22 = 1-2*(qx*qx+qy*qy);
    float t0 = s0*s0, t1 = s1*s1, t2 = s2*s2;
    float C00 = R00*R00*t0 + R01*R01*t1 + R02*R02*t2;
    float C01 = R00*R10*t0 + R01*R11*t1 + R02*R12*t2;
    float C02 = R00*R20*t0 + R01*R21*t1 + R02*R22*t2;
    float C11 = R10*R10*t0 + R11*R11*t1 + R12*R12*t2;
    float C12 = R10*R20*t0 + R11*R21*t1 + R12*R22*t2;
    float C22 = R20*R20*t0 + R21*R21*t1 + R22*R22*t2;

    float v0 = C00*rx + C01*ry + C02*rz;
    float v1 = C01*rx + C11*ry + C12*rz;
    float v2 = C02*rx + C12*ry + C22*rz;
    float ca = rx*v0 + ry*v1 + rz*v2;
    float cb = ux*v0 + uy*v1 + uz*v2;
    float w0 = C00*ux + C01*uy + C02*uz;
    float w1 = C01*ux + C11*uy + C12*uz;
    float w2 = C02*ux + C12*uy + C22*uz;
    float cd = ux*w0 + uy*w1 + uz*w2;

    float z2 = fmaxf(d*d, 0.01f);
    float sc = (IMGF * IMGF) / z2;
    float a  = ca*sc + 0.3f;
    float b  = cb*sc;
    float dd = cd*sc + 0.3f;
    float det  = fmaxf(a*dd - b*b, 1e-6f);
    float idet = 1.0f / det;

    bool valid = (d > 0.1f) && (m2dx > -IMGF) && (m2dx < 2.0f*IMGF)
                            && (m2dy > -IMGF) && (m2dy < 2.0f*IMGF);

    float op = 1.0f / (1.0f + expf(-opacity_logit[i]));
    const float L2E = 1.4426950408889634f;
    float A2 = -0.5f * L2E * dd * idet;
    float B2 =          L2E * b  * idet;
    float D2 = -0.5f * L2E * a  * idet;
    float L  = valid ? log2f(op) : -1e10f;

    float cr = 1.0f / (1.0f + expf(-color_pre[3*i+0]));
    float cg = 1.0f / (1.0f + expf(-color_pre[3*i+1]));
    float cl = 1.0f / (1.0f + expf(-color_pre[3*i+2]));

    unsigned int w6 = f32_bf16(cr) | (f32_bf16(cg) << 16);
    unsigned int w7 = f32_bf16(cl);

    float4* r4 = (float4*)(rec + RECF*i);
    r4[0] = make_float4(m2dx, m2dy, A2, B2);
    r4[1] = make_float4(D2, L, __uint_as_float(w6), __uint_as_float(w7));

    unsigned int ub   = __float_as_uint(d);
    unsigned int mask = ((unsigned int)((int)ub >> 31)) | 0x80000000u;
    keys[i] = ((unsigned long long)(ub ^ mask) << 32) | (unsigned int)i;
}

// O(N^2) stable rank sort: 64 blocks x 256; 8 threads per gaussian, each
// counting a 256-key segment (seg-skewed LDS reads), 3-step shfl combine;
// 8 threads cooperatively copy the 32B record to the round-major slot.
__global__ void __launch_bounds__(256)
gs_rank_scatter(const unsigned long long* __restrict__ keys,
                const float* __restrict__ rec,
                float* __restrict__ srec)
{
    __shared__ __align__(16) unsigned long long sk[N_G];
    int t = threadIdx.x;

    const ulonglong2* k2 = (const ulonglong2*)keys;
    ulonglong2* s2 = (ulonglong2*)sk;
    #pragma unroll
    for (int q = 0; q < 4; ++q) s2[t + q*256] = k2[t + q*256];   // 16 KB
    __syncthreads();

    int g   = (blockIdx.x << 5) | (t >> 3);       // 32 gaussians per block
    int seg = t & 7;                              // 8 segments x 256 keys
    unsigned long long ki = sk[g];
    const ulonglong2* sseg = (const ulonglong2*)(sk + (seg << 8));
    int rank = 0;
    #pragma unroll 8
    for (int j = 0; j < 128; ++j) {
        ulonglong2 a = sseg[(j + seg * 17) & 127];   // skew: distinct banks
        rank += (int)(a.x < ki) + (int)(a.y < ki);
    }
    rank += __shfl_xor(rank, 1);
    rank += __shfl_xor(rank, 2);
    rank += __shfl_xor(rank, 4);

    // round-major slot: round = rank>>9, step = rank&7, lane = (rank>>3)&63
    int slot = (rank & ~511) | ((rank & 7) << 6) | ((rank >> 3) & 63);
    srec[slot * RECF + seg] = rec[g * RECF + seg];
}

// Scan-form compositing, 4 rounds of 512 ranks, FOUR pixels per wave.
// Per round: 8 record loads (amortized over 4 px), colors kept in registers;
// wave prefix-product scan -> Tin; descending local pass (no loads);
// wave suffix scan -> S_out, M; fold into carries. Final single wave-reduce.
__global__ void __launch_bounds__(256)
gs_raster(const float* __restrict__ srec, float* __restrict__ out)
{
    int tid  = threadIdx.x;
    int lane = tid & 63;
    int wave = (blockIdx.x << 2) | (tid >> 6);    // 0..4095
    int p0   = wave * 4;                          // four pixels, same row
    float px0 = (float)(p0 & 127);
    float px1 = px0 + 1.0f, px2 = px0 + 2.0f, px3 = px0 + 3.0f;
    float py  = (float)(p0 >> 7);

    float G0=1.0f, G1=1.0f, G2=1.0f, G3=1.0f;         // prod(1-u)
    float Tc0=1.0f, Tc1=1.0f, Tc2=1.0f, Tc3=1.0f;     // prod(1-alpha)
    float Ar0=0.0f, Ag0=0.0f, Ab0=0.0f;               // deferred contribs
    float Ar1=0.0f, Ag1=0.0f, Ab1=0.0f;
    float Ar2=0.0f, Ag2=0.0f, Ab2=0.0f;
    float Ar3=0.0f, Ag3=0.0f, Ab3=0.0f;

    #pragma unroll 1
    for (int r = 0; r < 4; ++r) {
        const float* base = srec + (size_t)((r << 9) | lane) * RECF;

        // ---- pass 1: alphas + lane prefix products; keep colors ----
        float vA[8], vB[8], c6[8], c7[8];
        float P0=1.0f, P1=1.0f, P2=1.0f, P3=1.0f;
        #pragma unroll
        for (int i = 0; i < 8; ++i) {
            const float* rp = base + (size_t)(i << 6) * RECF;
            float4 ra = *(const float4*)rp;           // mux,muy,A2,B2
            float4 rb = *(const float4*)(rp + 4);     // D2,L,c6,c7
            c6[i] = rb.z;  c7[i] = rb.w;
            float dy   = py - ra.y;
            float b2dy = ra.w * dy;
            float t2   = fmaf(rb.x * dy, dy, rb.y);
            float dx0 = px0 - ra.x, dx1 = px1 - ra.x;
            float dx2 = px2 - ra.x, dx3 = px3 - ra.x;
            float q0 = fmaf(dx0, fmaf(ra.z, dx0, b2dy), t2);
            float q1 = fmaf(dx1, fmaf(ra.z, dx1, b2dy), t2);
            float q2 = fmaf(dx2, fmaf(ra.z, dx2, b2dy), t2);
            float q3 = fmaf(dx3, fmaf(ra.z, dx3, b2dy), t2);
            float a0 = fminf(__builtin_amdgcn_exp2f(q0), 0.99f);
            float a1 = fminf(__builtin_amdgcn_exp2f(q1), 0.99f);
            float a2 = fminf(__builtin_amdgcn_exp2f(q2), 0.99f);
            float a3 = fminf(__builtin_amdgcn_exp2f(q3), 0.99f);
            float u0 = P0 * a0;  P0 *= (1.0f - a0);
            float u1 = P1 * a1;  P1 *= (1.0f - a1);
            float u2 = P2 * a2;  P2 *= (1.0f - a2);
            float u3 = P3 * a3;  P3 *= (1.0f - a3);
            H2U hA; hA.h2 = __builtin_amdgcn_cvt_pkrtz(u0, u1);  vA[i] = hA.f;
            H2U hB; hB.h2 = __builtin_amdgcn_cvt_pkrtz(u2, u3);  vB[i] = hB.f;
        }

        // ---- wave inclusive prefix product of P -> Tin; round totals ----
        float sp0=P0, sp1=P1, sp2=P2, sp3=P3;
        #pragma unroll
        for (int d = 1; d < 64; d <<= 1) {
            float y0=__shfl_up(sp0,d), y1=__shfl_up(sp1,d);
            float y2=__shfl_up(sp2,d), y3=__shfl_up(sp3,d);
            if (lane >= d) { sp0*=y0; sp1*=y1; sp2*=y2; sp3*=y3; }
        }
        float e0=__shfl_up(sp0,1), e1=__shfl_up(sp1,1);
        float e2=__shfl_up(sp2,1), e3=__shfl_up(sp3,1);
        float Tin0 = Tc0 * ((lane==0)?1.0f:e0);
        float Tin1 = Tc1 * ((lane==0)?1.0f:e1);
        float Tin2 = Tc2 * ((lane==0)?1.0f:e2);
        float Tin3 = Tc3 * ((lane==0)?1.0f:e3);
        float tot0=__shfl(sp0,63), tot1=__shfl(sp1,63);
        float tot2=__shfl(sp2,63), tot3=__shfl(sp3,63);

        // ---- pass 2 (descending, register-only): contrib + B ----
        float Sl0=1.0f, Sl1=1.0f, Sl2=1.0f, Sl3=1.0f;
        float cr0=0,cg0=0,cb0=0, cr1=0,cg1=0,cb1=0;
        float cr2=0,cg2=0,cb2=0, cr3=0,cg3=0,cb3=0;
        #pragma unroll
        for (int i = 7; i >= 0; --i) {
            unsigned int w6 = __float_as_uint(c6[i]);
            unsigned int w7 = __float_as_uint(c7[i]);
            float ccr = __uint_as_float(w6 << 16);    // bf16 -> f32: 1 shl
            float ccg = __uint_as_float(w6 & 0xFFFF0000u);
            float ccb = __uint_as_float(w7 << 16);
            H2U hA; hA.f = vA[i];
            H2U hB; hB.f = vB[i];
            float u0 = Tin0 * (float)hA.h2.x;
            float us0 = u0 * Sl0;
            cr0 = fmaf(us0, ccr, cr0); cg0 = fmaf(us0, ccg, cg0); cb0 = fmaf(us0, ccb, cb0);
            Sl0 = fmaf(-u0, Sl0, Sl0);
            float u1 = Tin1 * (float)hA.h2.y;
            float us1 = u1 * Sl1;
            cr1 = fmaf(us1, ccr, cr1); cg1 = fmaf(us1, ccg, cg1); cb1 = fmaf(us1, ccb, cb1);
            Sl1 = fmaf(-u1, Sl1, Sl1);
            float u2 = Tin2 * (float)hB.h2.x;
            float us2 = u2 * Sl2;
            cr2 = fmaf(us2, ccr, cr2); cg2 = fmaf(us2, ccg, cg2); cb2 = fmaf(us2, ccb, cb2);
            Sl2 = fmaf(-u2, Sl2, Sl2);
            float u3 = Tin3 * (float)hB.h2.y;
            float us3 = u3 * Sl3;
            cr3 = fmaf(us3, ccr, cr3); cg3 = fmaf(us3, ccg, cg3); cb3 = fmaf(us3, ccb, cb3);
            Sl3 = fmaf(-u3, Sl3, Sl3);
        }

        // ---- wave inclusive suffix product of B -> S_out, M ----
        float ss0=Sl0, ss1=Sl1, ss2=Sl2, ss3=Sl3;
        #pragma unroll
        for (int d = 1; d < 64; d <<= 1) {
            float y0=__shfl_down(ss0,d), y1=__shfl_down(ss1,d);
            float y2=__shfl_down(ss2,d), y3=__shfl_down(ss3,d);
            if (lane + d < 64) { ss0*=y0; ss1*=y1; ss2*=y2; ss3*=y3; }
        }
        float f0=__shfl_down(ss0,1), f1=__shfl_down(ss1,1);
        float f2=__shfl_down(ss2,1), f3=__shfl_down(ss3,1);
        float So0 = (lane==63)?1.0f:f0;
        float So1 = (lane==63)?1.0f:f1;
        float So2 = (lane==63)?1.0f:f2;
        float So3 = (lane==63)?1.0f:f3;
        float M0=__shfl(ss0,0), M1=__shfl(ss1,0);
        float M2=__shfl(ss2,0), M3=__shfl(ss3,0);

        // ---- fold round into carries ----
        Ar0 = fmaf(Ar0, M0, cr0 * So0);
        Ag0 = fmaf(Ag0, M0, cg0 * So0);
        Ab0 = fmaf(Ab0, M0, cb0 * So0);
        Ar1 = fmaf(Ar1, M1, cr1 * So1);
        Ag1 = fmaf(Ag1, M1, cg1 * So1);
        Ab1 = fmaf(Ab1, M1, cb1 * So1);
        Ar2 = fmaf(Ar2, M2, cr2 * So2);
        Ag2 = fmaf(Ag2, M2, cg2 * So2);
        Ab2 = fmaf(Ab2, M2, cb2 * So2);
        Ar3 = fmaf(Ar3, M3, cr3 * So3);
        Ag3 = fmaf(Ag3, M3, cg3 * So3);
        Ab3 = fmaf(Ab3, M3, cb3 * So3);
        G0 *= M0;  G1 *= M1;  G2 *= M2;  G3 *= M3;
        Tc0 *= tot0;  Tc1 *= tot1;  Tc2 *= tot2;  Tc3 *= tot3;
    }

    // ---- wave sum-reduce the deferred contributions ----
    #pragma unroll
    for (int d = 1; d < 64; d <<= 1) {
        Ar0 += __shfl_xor(Ar0, d); Ag0 += __shfl_xor(Ag0, d); Ab0 += __shfl_xor(Ab0, d);
        Ar1 += __shfl_xor(Ar1, d); Ag1 += __shfl_xor(Ag1, d); Ab1 += __shfl_xor(Ab1, d);
        Ar2 += __shfl_xor(Ar2, d); Ag2 += __shfl_xor(Ag2, d); Ab2 += __shfl_xor(Ab2, d);
        Ar3 += __shfl_xor(Ar3, d); Ag3 += __shfl_xor(Ag3, d); Ab3 += __shfl_xor(Ab3, d);
    }

    if (lane == 0) {
        float* o0 = out + (size_t)p0 * 3;
        o0[0]  = fminf(fmaxf(G0 + Ar0, 0.0f), 1.0f);
        o0[1]  = fminf(fmaxf(G0 + Ag0, 0.0f), 1.0f);
        o0[2]  = fminf(fmaxf(G0 + Ab0, 0.0f), 1.0f);
        o0[3]  = fminf(fmaxf(G1 + Ar1, 0.0f), 1.0f);
        o0[4]  = fminf(fmaxf(G1 + Ag1, 0.0f), 1.0f);
        o0[5]  = fminf(fmaxf(G1 + Ab1, 0.0f), 1.0f);
        o0[6]  = fminf(fmaxf(G2 + Ar2, 0.0f), 1.0f);
        o0[7]  = fminf(fmaxf(G2 + Ag2, 0.0f), 1.0f);
        o0[8]  = fminf(fmaxf(G2 + Ab2, 0.0f), 1.0f);
        o0[9]  = fminf(fmaxf(G3 + Ar3, 0.0f), 1.0f);
        o0[10] = fminf(fmaxf(G3 + Ag3, 0.0f), 1.0f);
        o0[11] = fminf(fmaxf(G3 + Ab3, 0.0f), 1.0f);
    }
}

extern "C" void kernel_launch(void* const* d_in, const int* in_sizes, int n_in,
                              void* d_out, int out_size, void* d_ws, size_t ws_size,
                              hipStream_t stream)
{
    const float* means         = (const float*)d_in[0];
    const float* log_scales    = (const float*)d_in[1];
    const float* rotations     = (const float*)d_in[2];
    const float* opacity_logit = (const float*)d_in[3];
    const float* color_pre     = (const float*)d_in[4];
    const float* cam_pos       = (const float*)d_in[5];
    const float* look_at       = (const float*)d_in[6];
    float* out = (float*)d_out;

    char* ws = (char*)d_ws;
    float*              rec  = (float*)(ws);                         // 64 KB
    unsigned long long* keys = (unsigned long long*)(ws + 65536);    // 16 KB
    float*              srec = (float*)(ws + 65536 + 16384);         // 64 KB

    hipLaunchKernelGGL(gs_preprocess, dim3(N_G / 256), dim3(256), 0, stream,
                       means, log_scales, rotations, opacity_logit, color_pre,
                       cam_pos, look_at, rec, keys);
    hipLaunchKernelGGL(gs_rank_scatter, dim3(N_G / 32), dim3(256), 0, stream,
                       keys, rec, srec);
    // 16384 px / 4 px-per-wave = 4096 waves; 4 waves/block -> 1024 blocks
    hipLaunchKernelGGL(gs_raster, dim3(1024), dim3(256), 0, stream,
                       srec, out);
}

// Round 18
// 94.869 us; speedup vs baseline: 1.1286x; 1.0242x over previous
//
#include <hip/hip_runtime.h>
#include <hip/hip_bf16.h>
#include <hip/hip_fp16.h>

#define N_G   2048
#define IMGF  128.0f
#define RECF  8          // floats per gaussian record (2 x float4, 32 B)

// record layout (8 floats):
//  [0]=mu_x [1]=mu_y [2]=A2 [3]=B2 [4]=D2 [5]=L
//  [6]=bf16pack(cr|cg<<16) [7]=bf16pack(cb)
// p2 = A2*dx^2 + B2*dx*dy + D2*dy^2 + L ; alpha = min(exp2(p2), 0.99)
// L = log2(opacity) or -1e10 if invalid (exp2 -> 0 reproduces valid-mask)
//
// TWO-KERNEL PIPELINE (dispatch count is now first-order):
//  K1 gs_prep_rank: 64 blocks x 256. Each block recomputes all 2048 depth
//     keys into LDS (cheap: depth = fwd-dot only), ranks its 32 gaussians
//     (O(N^2) stable, seg-skewed LDS compares, shfl combine), computes the
//     full record (8 threads/gaussian redundantly) and scatters each float
//     to the round-major slot. No keys global roundtrip.
//  K2 gs_raster: scan-form compositing, 4 rounds of 512, 4 px/wave.
//     s(rank) = (rank&~511) | ((rank&7)<<6) | ((rank>>3)&63): at (round,i)
//     lanes read 64 consecutive 32B records (coalesced).
//
// Sort key: u64 = mono32(depth) << 32 | idx -> stable argsort, 1 u64 compare.

typedef __fp16 half2_v __attribute__((ext_vector_type(2)));
union H2U { half2_v h2; float f; unsigned int u; };

static __device__ __forceinline__ unsigned int f32_bf16(float f) {
    unsigned int u = __float_as_uint(f);
    return (u + 0x7FFFu + ((u >> 16) & 1u)) >> 16;      // RNE, finite inputs
}

// fused preprocess + rank + scatter
__global__ void __launch_bounds__(256)
gs_prep_rank(const float* __restrict__ means,
             const float* __restrict__ log_scales,
             const float* __restrict__ rotations,
             const float* __restrict__ opacity_logit,
             const float* __restrict__ color_pre,
             const float* __restrict__ cam_pos,
             const float* __restrict__ look_at,
             float* __restrict__ srec)
{
    __shared__ __align__(16) unsigned long long sk[N_G];
    int t = threadIdx.x;

    // ---- camera basis (uniform) ----
    float cx = cam_pos[0], cy = cam_pos[1], cz = cam_pos[2];
    float fx = look_at[0] - cx, fy = look_at[1] - cy, fz = look_at[2] - cz;
    float fn = 1.0f / sqrtf(fx*fx + fy*fy + fz*fz);
    fx *= fn; fy *= fn; fz *= fn;
    float rx = -fz, ry = 0.0f, rz = fx;                 // cross(fwd,(0,1,0))
    float rn = 1.0f / sqrtf(rx*rx + ry*ry + rz*rz);
    rx *= rn; ry *= rn; rz *= rn;
    float ux = ry*fz - rz*fy, uy = rz*fx - rx*fz, uz = rx*fy - ry*fx;

    // ---- all 2048 depth keys -> LDS (8 per thread) ----
    #pragma unroll
    for (int q = 0; q < 8; ++q) {
        int g = t + q * 256;
        float mx = means[3*g+0] - cx;
        float my = means[3*g+1] - cy;
        float mz = means[3*g+2] - cz;
        float d  = fx*mx + fy*my + fz*mz;    // depth = -(-fwd dot) = fwd dot
        unsigned int ub   = __float_as_uint(d);
        unsigned int mask = ((unsigned int)((int)ub >> 31)) | 0x80000000u;
        sk[g] = ((unsigned long long)(ub ^ mask) << 32) | (unsigned int)g;
    }
    __syncthreads();

    // ---- rank own gaussian (8 threads each, seg-partitioned) ----
    int g   = (blockIdx.x << 5) | (t >> 3);   // 32 gaussians per block
    int seg = t & 7;                          // 8 segments x 256 keys
    unsigned long long ki = sk[g];
    const ulonglong2* sseg = (const ulonglong2*)(sk + (seg << 8));
    int rank = 0;
    #pragma unroll 8
    for (int j = 0; j < 128; ++j) {
        ulonglong2 a = sseg[(j + seg * 17) & 127];   // skew: distinct banks
        rank += (int)(a.x < ki) + (int)(a.y < ki);
    }
    rank += __shfl_xor(rank, 1);
    rank += __shfl_xor(rank, 2);
    rank += __shfl_xor(rank, 4);

    // ---- full record for gaussian g (redundant x8, one float each) ----
    float mx = means[3*g+0] - cx, my = means[3*g+1] - cy, mz = means[3*g+2] - cz;
    float m0 =  rx*mx + ry*my + rz*mz;
    float m1 =  ux*mx + uy*my + uz*mz;
    float m2 = -(fx*mx + fy*my + fz*mz);
    float d  = -m2;
    float invz = 1.0f / (-m2 + 1e-8f);
    float m2dx =  (m0 * invz) * IMGF + IMGF * 0.5f;
    float m2dy = -(m1 * invz) * IMGF + IMGF * 0.5f;

    float s0 = expf(log_scales[3*g+0]);
    float s1 = expf(log_scales[3*g+1]);
    float s2 = expf(log_scales[3*g+2]);
    float qw = rotations[4*g+0], qx = rotations[4*g+1],
          qy = rotations[4*g+2], qz = rotations[4*g+3];
    float qn = 1.0f / sqrtf(qw*qw + qx*qx + qy*qy + qz*qz);
    qw *= qn; qx *= qn; qy *= qn; qz *= qn;
    float R00 = 1-2*(qy*qy+qz*qz), R01 = 2*(qx*qy-qw*qz), R02 = 2*(qx*qz+qw*qy);
    float R10 = 2*(qx*qy+qw*qz), R11 = 1-2*(qx*qx+qz*qz), R12 = 2*(qy*qz-qw*qx);
    float R20 = 2*(qx*qz-qw*qy), R21 = 2*(qy*qz+qw*qx), R22 = 1-2*(qx*qx+qy*qy);
    float t0 = s0*s0, t1 = s1*s1, t2 = s2*s2;
    float C00 = R00*R00*t0 + R01*R01*t1 + R02*R02*t2;
    float C01 = R00*R10*t0 + R01*R11*t1 + R02*R12*t2;
    float C02 = R00*R20*t0 + R01*R21*t1 + R02*R22*t2;
    float C11 = R10*R10*t0 + R11*R11*t1 + R12*R12*t2;
    float C12 = R10*R20*t0 + R11*R21*t1 + R12*R22*t2;
    float C22 = R20*R20*t0 + R21*R21*t1 + R22*R22*t2;

    float v0 = C00*rx + C01*ry + C02*rz;
    float v1 = C01*rx + C11*ry + C12*rz;
    float v2 = C02*rx + C12*ry + C22*rz;
    float ca = rx*v0 + ry*v1 + rz*v2;
    float cb = ux*v0 + uy*v1 + uz*v2;
    float w0 = C00*ux + C01*uy + C02*uz;
    float w1 = C01*ux + C11*uy + C12*uz;
    float w2 = C02*ux + C12*uy + C22*uz;
    float cd = ux*w0 + uy*w1 + uz*w2;

    float z2 = fmaxf(d*d, 0.01f);
    float sc = (IMGF * IMGF) / z2;
    float a  = ca*sc + 0.3f;
    float b  = cb*sc;
    float dd = cd*sc + 0.3f;
    float det  = fmaxf(a*dd - b*b, 1e-6f);
    float idet = 1.0f / det;

    bool valid = (d > 0.1f) && (m2dx > -IMGF) && (m2dx < 2.0f*IMGF)
                            && (m2dy > -IMGF) && (m2dy < 2.0f*IMGF);

    float op = 1.0f / (1.0f + expf(-opacity_logit[g]));
    const float L2E = 1.4426950408889634f;
    float A2 = -0.5f * L2E * dd * idet;
    float B2 =          L2E * b  * idet;
    float D2 = -0.5f * L2E * a  * idet;
    float L  = valid ? log2f(op) : -1e10f;

    float cr = 1.0f / (1.0f + expf(-color_pre[3*g+0]));
    float cg = 1.0f / (1.0f + expf(-color_pre[3*g+1]));
    float cl = 1.0f / (1.0f + expf(-color_pre[3*g+2]));

    float w6f = __uint_as_float(f32_bf16(cr) | (f32_bf16(cg) << 16));
    float w7f = __uint_as_float(f32_bf16(cl));

    // seg-th record float via cndmask chain (no runtime-indexed array)
    float lo = (seg < 2) ? ((seg == 0) ? m2dx : m2dy)
                         : ((seg == 2) ? A2   : B2);
    float hi = (seg < 6) ? ((seg == 4) ? D2   : L)
                         : ((seg == 6) ? w6f  : w7f);
    float rv = (seg < 4) ? lo : hi;

    // round-major slot: round = rank>>9, step = rank&7, lane = (rank>>3)&63
    int slot = (rank & ~511) | ((rank & 7) << 6) | ((rank >> 3) & 63);
    srec[slot * RECF + seg] = rv;
}

// Scan-form compositing, 4 rounds of 512 ranks, FOUR pixels per wave.
// Per round: 8 record loads (amortized over 4 px), colors kept in registers;
// wave prefix-product scan -> Tin; descending local pass (no loads);
// wave suffix scan -> S_out, M; fold into carries. Final single wave-reduce.
__global__ void __launch_bounds__(256)
gs_raster(const float* __restrict__ srec, float* __restrict__ out)
{
    int tid  = threadIdx.x;
    int lane = tid & 63;
    int wave = (blockIdx.x << 2) | (tid >> 6);    // 0..4095
    int p0   = wave * 4;                          // four pixels, same row
    float px0 = (float)(p0 & 127);
    float px1 = px0 + 1.0f, px2 = px0 + 2.0f, px3 = px0 + 3.0f;
    float py  = (float)(p0 >> 7);

    float G0=1.0f, G1=1.0f, G2=1.0f, G3=1.0f;         // prod(1-u)
    float Tc0=1.0f, Tc1=1.0f, Tc2=1.0f, Tc3=1.0f;     // prod(1-alpha)
    float Ar0=0.0f, Ag0=0.0f, Ab0=0.0f;               // deferred contribs
    float Ar1=0.0f, Ag1=0.0f, Ab1=0.0f;
    float Ar2=0.0f, Ag2=0.0f, Ab2=0.0f;
    float Ar3=0.0f, Ag3=0.0f, Ab3=0.0f;

    #pragma unroll 1
    for (int r = 0; r < 4; ++r) {
        const float* base = srec + (size_t)((r << 9) | lane) * RECF;

        // ---- pass 1: alphas + lane prefix products; keep colors ----
        float vA[8], vB[8], c6[8], c7[8];
        float P0=1.0f, P1=1.0f, P2=1.0f, P3=1.0f;
        #pragma unroll
        for (int i = 0; i < 8; ++i) {
            const float* rp = base + (size_t)(i << 6) * RECF;
            float4 ra = *(const float4*)rp;           // mux,muy,A2,B2
            float4 rb = *(const float4*)(rp + 4);     // D2,L,c6,c7
            c6[i] = rb.z;  c7[i] = rb.w;
            float dy   = py - ra.y;
            float b2dy = ra.w * dy;
            float t2   = fmaf(rb.x * dy, dy, rb.y);
            float dx0 = px0 - ra.x, dx1 = px1 - ra.x;
            float dx2 = px2 - ra.x, dx3 = px3 - ra.x;
            float q0 = fmaf(dx0, fmaf(ra.z, dx0, b2dy), t2);
            float q1 = fmaf(dx1, fmaf(ra.z, dx1, b2dy), t2);
            float q2 = fmaf(dx2, fmaf(ra.z, dx2, b2dy), t2);
            float q3 = fmaf(dx3, fmaf(ra.z, dx3, b2dy), t2);
            float a0 = fminf(__builtin_amdgcn_exp2f(q0), 0.99f);
            float a1 = fminf(__builtin_amdgcn_exp2f(q1), 0.99f);
            float a2 = fminf(__builtin_amdgcn_exp2f(q2), 0.99f);
            float a3 = fminf(__builtin_amdgcn_exp2f(q3), 0.99f);
            float u0 = P0 * a0;  P0 *= (1.0f - a0);
            float u1 = P1 * a1;  P1 *= (1.0f - a1);
            float u2 = P2 * a2;  P2 *= (1.0f - a2);
            float u3 = P3 * a3;  P3 *= (1.0f - a3);
            H2U hA; hA.h2 = __builtin_amdgcn_cvt_pkrtz(u0, u1);  vA[i] = hA.f;
            H2U hB; hB.h2 = __builtin_amdgcn_cvt_pkrtz(u2, u3);  vB[i] = hB.f;
        }

        // ---- wave inclusive prefix product of P -> Tin; round totals ----
        float sp0=P0, sp1=P1, sp2=P2, sp3=P3;
        #pragma unroll
        for (int d = 1; d < 64; d <<= 1) {
            float y0=__shfl_up(sp0,d), y1=__shfl_up(sp1,d);
            float y2=__shfl_up(sp2,d), y3=__shfl_up(sp3,d);
            if (lane >= d) { sp0*=y0; sp1*=y1; sp2*=y2; sp3*=y3; }
        }
        float e0=__shfl_up(sp0,1), e1=__shfl_up(sp1,1);
        float e2=__shfl_up(sp2,1), e3=__shfl_up(sp3,1);
        float Tin0 = Tc0 * ((lane==0)?1.0f:e0);
        float Tin1 = Tc1 * ((lane==0)?1.0f:e1);
        float Tin2 = Tc2 * ((lane==0)?1.0f:e2);
        float Tin3 = Tc3 * ((lane==0)?1.0f:e3);
        float tot0=__shfl(sp0,63), tot1=__shfl(sp1,63);
        float tot2=__shfl(sp2,63), tot3=__shfl(sp3,63);

        // ---- pass 2 (descending, register-only): contrib + B ----
        float Sl0=1.0f, Sl1=1.0f, Sl2=1.0f, Sl3=1.0f;
        float cr0=0,cg0=0,cb0=0, cr1=0,cg1=0,cb1=0;
        float cr2=0,cg2=0,cb2=0, cr3=0,cg3=0,cb3=0;
        #pragma unroll
        for (int i = 7; i >= 0; --i) {
            unsigned int w6 = __float_as_uint(c6[i]);
            unsigned int w7 = __float_as_uint(c7[i]);
            float ccr = __uint_as_float(w6 << 16);    // bf16 -> f32: 1 shl
            float ccg = __uint_as_float(w6 & 0xFFFF0000u);
            float ccb = __uint_as_float(w7 << 16);
            H2U hA; hA.f = vA[i];
            H2U hB; hB.f = vB[i];
            float u0 = Tin0 * (float)hA.h2.x;
            float us0 = u0 * Sl0;
            cr0 = fmaf(us0, ccr, cr0); cg0 = fmaf(us0, ccg, cg0); cb0 = fmaf(us0, ccb, cb0);
            Sl0 = fmaf(-u0, Sl0, Sl0);
            float u1 = Tin1 * (float)hA.h2.y;
            float us1 = u1 * Sl1;
            cr1 = fmaf(us1, ccr, cr1); cg1 = fmaf(us1, ccg, cg1); cb1 = fmaf(us1, ccb, cb1);
            Sl1 = fmaf(-u1, Sl1, Sl1);
            float u2 = Tin2 * (float)hB.h2.x;
            float us2 = u2 * Sl2;
            cr2 = fmaf(us2, ccr, cr2); cg2 = fmaf(us2, ccg, cg2); cb2 = fmaf(us2, ccb, cb2);
            Sl2 = fmaf(-u2, Sl2, Sl2);
            float u3 = Tin3 * (float)hB.h2.y;
            float us3 = u3 * Sl3;
            cr3 = fmaf(us3, ccr, cr3); cg3 = fmaf(us3, ccg, cg3); cb3 = fmaf(us3, ccb, cb3);
            Sl3 = fmaf(-u3, Sl3, Sl3);
        }

        // ---- wave inclusive suffix product of B -> S_out, M ----
        float ss0=Sl0, ss1=Sl1, ss2=Sl2, ss3=Sl3;
        #pragma unroll
        for (int d = 1; d < 64; d <<= 1) {
            float y0=__shfl_down(ss0,d), y1=__shfl_down(ss1,d);
            float y2=__shfl_down(ss2,d), y3=__shfl_down(ss3,d);
            if (lane + d < 64) { ss0*=y0; ss1*=y1; ss2*=y2; ss3*=y3; }
        }
        float f0=__shfl_down(ss0,1), f1=__shfl_down(ss1,1);
        float f2=__shfl_down(ss2,1), f3=__shfl_down(ss3,1);
        float So0 = (lane==63)?1.0f:f0;
        float So1 = (lane==63)?1.0f:f1;
        float So2 = (lane==63)?1.0f:f2;
        float So3 = (lane==63)?1.0f:f3;
        float M0=__shfl(ss0,0), M1=__shfl(ss1,0);
        float M2=__shfl(ss2,0), M3=__shfl(ss3,0);

        // ---- fold round into carries ----
        Ar0 = fmaf(Ar0, M0, cr0 * So0);
        Ag0 = fmaf(Ag0, M0, cg0 * So0);
        Ab0 = fmaf(Ab0, M0, cb0 * So0);
        Ar1 = fmaf(Ar1, M1, cr1 * So1);
        Ag1 = fmaf(Ag1, M1, cg1 * So1);
        Ab1 = fmaf(Ab1, M1, cb1 * So1);
        Ar2 = fmaf(Ar2, M2, cr2 * So2);
        Ag2 = fmaf(Ag2, M2, cg2 * So2);
        Ab2 = fmaf(Ab2, M2, cb2 * So2);
        Ar3 = fmaf(Ar3, M3, cr3 * So3);
        Ag3 = fmaf(Ag3, M3, cg3 * So3);
        Ab3 = fmaf(Ab3, M3, cb3 * So3);
        G0 *= M0;  G1 *= M1;  G2 *= M2;  G3 *= M3;
        Tc0 *= tot0;  Tc1 *= tot1;  Tc2 *= tot2;  Tc3 *= tot3;
    }

    // ---- wave sum-reduce the deferred contributions ----
    #pragma unroll
    for (int d = 1; d < 64; d <<= 1) {
        Ar0 += __shfl_xor(Ar0, d); Ag0 += __shfl_xor(Ag0, d); Ab0 += __shfl_xor(Ab0, d);
        Ar1 += __shfl_xor(Ar1, d); Ag1 += __shfl_xor(Ag1, d); Ab1 += __shfl_xor(Ab1, d);
        Ar2 += __shfl_xor(Ar2, d); Ag2 += __shfl_xor(Ag2, d); Ab2 += __shfl_xor(Ab2, d);
        Ar3 += __shfl_xor(Ar3, d); Ag3 += __shfl_xor(Ag3, d); Ab3 += __shfl_xor(Ab3, d);
    }

    if (lane == 0) {
        float* o0 = out + (size_t)p0 * 3;
        o0[0]  = fminf(fmaxf(G0 + Ar0, 0.0f), 1.0f);
        o0[1]  = fminf(fmaxf(G0 + Ag0, 0.0f), 1.0f);
        o0[2]  = fminf(fmaxf(G0 + Ab0, 0.0f), 1.0f);
        o0[3]  = fminf(fmaxf(G1 + Ar1, 0.0f), 1.0f);
        o0[4]  = fminf(fmaxf(G1 + Ag1, 0.0f), 1.0f);
        o0[5]  = fminf(fmaxf(G1 + Ab1, 0.0f), 1.0f);
        o0[6]  = fminf(fmaxf(G2 + Ar2, 0.0f), 1.0f);
        o0[7]  = fminf(fmaxf(G2 + Ag2, 0.0f), 1.0f);
        o0[8]  = fminf(fmaxf(G2 + Ab2, 0.0f), 1.0f);
        o0[9]  = fminf(fmaxf(G3 + Ar3, 0.0f), 1.0f);
        o0[10] = fminf(fmaxf(G3 + Ag3, 0.0f), 1.0f);
        o0[11] = fminf(fmaxf(G3 + Ab3, 0.0f), 1.0f);
    }
}

extern "C" void kernel_launch(void* const* d_in, const int* in_sizes, int n_in,
                              void* d_out, int out_size, void* d_ws, size_t ws_size,
                              hipStream_t stream)
{
    const float* means         = (const float*)d_in[0];
    const float* log_scales    = (const float*)d_in[1];
    const float* rotations     = (const float*)d_in[2];
    const float* opacity_logit = (const float*)d_in[3];
    const float* color_pre     = (const float*)d_in[4];
    const float* cam_pos       = (const float*)d_in[5];
    const float* look_at       = (const float*)d_in[6];
    float* out = (float*)d_out;

    float* srec = (float*)d_ws;                                      // 64 KB

    hipLaunchKernelGGL(gs_prep_rank, dim3(N_G / 32), dim3(256), 0, stream,
                       means, log_scales, rotations, opacity_logit, color_pre,
                       cam_pos, look_at, srec);
    // 16384 px / 4 px-per-wave = 4096 waves; 4 waves/block -> 1024 blocks
    hipLaunchKernelGGL(gs_raster, dim3(1024), dim3(256), 0, stream,
                       srec, out);
}

// Round 19
// 93.387 us; speedup vs baseline: 1.1465x; 1.0159x over previous
//
#include <hip/hip_runtime.h>
#include <hip/hip_bf16.h>
#include <hip/hip_fp16.h>

#define N_G   2048
#define IMGF  128.0f
#define RECF  8          // floats per gaussian record (2 x float4, 32 B)

// record layout (8 floats):
//  [0]=mu_x [1]=mu_y [2]=A2 [3]=B2 [4]=D2 [5]=L
//  [6]=bf16pack(cr|cg<<16) [7]=bf16pack(cb)
// p2 = A2*dx^2 + B2*dx*dy + D2*dy^2 + L ; alpha = min(exp2(p2), 0.99)
// L = log2(opacity) or -1e10 if invalid (exp2 -> 0 reproduces valid-mask)
//
// TWO-KERNEL PIPELINE:
//  K1 gs_prep_rank: 64 blocks x 256. Each block recomputes all 2048 depth
//     keys into LDS, ranks its 32 gaussians (O(N^2) stable, seg-skewed LDS
//     compares, shfl combine), computes the full record (8 threads/gaussian
//     redundantly) and scatters each float to the round-major slot.
//  K2 gs_raster: scan-form compositing, TWO rounds of 1024, 4 px/wave.
//     s(rank) = (rank&~1023) | ((rank&15)<<6) | ((rank>>4)&63): at (round,i)
//     lanes read 64 consecutive 32B records (coalesced); lane l owns the
//     contiguous rank range [1024r+16l, 1024r+16l+16) (scan order).
//     2 rounds (vs 4) halves the wave-scan phases and carry folds; vp/color
//     arrays [16] stay register-resident (~160 VGPR, 3 waves/SIMD).
//
// Sort key: u64 = mono32(depth) << 32 | idx -> stable argsort, 1 u64 compare.

typedef __fp16 half2_v __attribute__((ext_vector_type(2)));
union H2U { half2_v h2; float f; unsigned int u; };

static __device__ __forceinline__ unsigned int f32_bf16(float f) {
    unsigned int u = __float_as_uint(f);
    return (u + 0x7FFFu + ((u >> 16) & 1u)) >> 16;      // RNE, finite inputs
}

// fused preprocess + rank + scatter
__global__ void __launch_bounds__(256)
gs_prep_rank(const float* __restrict__ means,
             const float* __restrict__ log_scales,
             const float* __restrict__ rotations,
             const float* __restrict__ opacity_logit,
             const float* __restrict__ color_pre,
             const float* __restrict__ cam_pos,
             const float* __restrict__ look_at,
             float* __restrict__ srec)
{
    __shared__ __align__(16) unsigned long long sk[N_G];
    int t = threadIdx.x;

    // ---- camera basis (uniform) ----
    float cx = cam_pos[0], cy = cam_pos[1], cz = cam_pos[2];
    float fx = look_at[0] - cx, fy = look_at[1] - cy, fz = look_at[2] - cz;
    float fn = 1.0f / sqrtf(fx*fx + fy*fy + fz*fz);
    fx *= fn; fy *= fn; fz *= fn;
    float rx = -fz, ry = 0.0f, rz = fx;                 // cross(fwd,(0,1,0))
    float rn = 1.0f / sqrtf(rx*rx + ry*ry + rz*rz);
    rx *= rn; ry *= rn; rz *= rn;
    float ux = ry*fz - rz*fy, uy = rz*fx - rx*fz, uz = rx*fy - ry*fx;

    // ---- all 2048 depth keys -> LDS (8 per thread) ----
    #pragma unroll
    for (int q = 0; q < 8; ++q) {
        int g = t + q * 256;
        float mx = means[3*g+0] - cx;
        float my = means[3*g+1] - cy;
        float mz = means[3*g+2] - cz;
        float d  = fx*mx + fy*my + fz*mz;    // depth = fwd dot
        unsigned int ub   = __float_as_uint(d);
        unsigned int mask = ((unsigned int)((int)ub >> 31)) | 0x80000000u;
        sk[g] = ((unsigned long long)(ub ^ mask) << 32) | (unsigned int)g;
    }
    __syncthreads();

    // ---- rank own gaussian (8 threads each, seg-partitioned) ----
    int g   = (blockIdx.x << 5) | (t >> 3);   // 32 gaussians per block
    int seg = t & 7;                          // 8 segments x 256 keys
    unsigned long long ki = sk[g];
    const ulonglong2* sseg = (const ulonglong2*)(sk + (seg << 8));
    int rank = 0;
    #pragma unroll 8
    for (int j = 0; j < 128; ++j) {
        ulonglong2 a = sseg[(j + seg * 17) & 127];   // skew: distinct banks
        rank += (int)(a.x < ki) + (int)(a.y < ki);
    }
    rank += __shfl_xor(rank, 1);
    rank += __shfl_xor(rank, 2);
    rank += __shfl_xor(rank, 4);

    // ---- full record for gaussian g (redundant x8, one float each) ----
    float mx = means[3*g+0] - cx, my = means[3*g+1] - cy, mz = means[3*g+2] - cz;
    float m0 =  rx*mx + ry*my + rz*mz;
    float m1 =  ux*mx + uy*my + uz*mz;
    float m2 = -(fx*mx + fy*my + fz*mz);
    float d  = -m2;
    float invz = 1.0f / (-m2 + 1e-8f);
    float m2dx =  (m0 * invz) * IMGF + IMGF * 0.5f;
    float m2dy = -(m1 * invz) * IMGF + IMGF * 0.5f;

    float s0 = expf(log_scales[3*g+0]);
    float s1 = expf(log_scales[3*g+1]);
    float s2 = expf(log_scales[3*g+2]);
    float qw = rotations[4*g+0], qx = rotations[4*g+1],
          qy = rotations[4*g+2], qz = rotations[4*g+3];
    float qn = 1.0f / sqrtf(qw*qw + qx*qx + qy*qy + qz*qz);
    qw *= qn; qx *= qn; qy *= qn; qz *= qn;
    float R00 = 1-2*(qy*qy+qz*qz), R01 = 2*(qx*qy-qw*qz), R02 = 2*(qx*qz+qw*qy);
    float R10 = 2*(qx*qy+qw*qz), R11 = 1-2*(qx*qx+qz*qz), R12 = 2*(qy*qz-qw*qx);
    float R20 = 2*(qx*qz-qw*qy), R21 = 2*(qy*qz+qw*qx), R22 = 1-2*(qx*qx+qy*qy);
    float t0 = s0*s0, t1 = s1*s1, t2 = s2*s2;
    float C00 = R00*R00*t0 + R01*R01*t1 + R02*R02*t2;
    float C01 = R00*R10*t0 + R01*R11*t1 + R02*R12*t2;
    float C02 = R00*R20*t0 + R01*R21*t1 + R02*R22*t2;
    float C11 = R10*R10*t0 + R11*R11*t1 + R12*R12*t2;
    float C12 = R10*R20*t0 + R11*R21*t1 + R12*R22*t2;
    float C22 = R20*R20*t0 + R21*R21*t1 + R22*R22*t2;

    float v0 = C00*rx + C01*ry + C02*rz;
    float v1 = C01*rx + C11*ry + C12*rz;
    float v2 = C02*rx + C12*ry + C22*rz;
    float ca = rx*v0 + ry*v1 + rz*v2;
    float cb = ux*v0 + uy*v1 + uz*v2;
    float w0 = C00*ux + C01*uy + C02*uz;
    float w1 = C01*ux + C11*uy + C12*uz;
    float w2 = C02*ux + C12*uy + C22*uz;
    float cd = ux*w0 + uy*w1 + uz*w2;

    float z2 = fmaxf(d*d, 0.01f);
    float sc = (IMGF * IMGF) / z2;
    float a  = ca*sc + 0.3f;
    float b  = cb*sc;
    float dd = cd*sc + 0.3f;
    float det  = fmaxf(a*dd - b*b, 1e-6f);
    float idet = 1.0f / det;

    bool valid = (d > 0.1f) && (m2dx > -IMGF) && (m2dx < 2.0f*IMGF)
                            && (m2dy > -IMGF) && (m2dy < 2.0f*IMGF);

    float op = 1.0f / (1.0f + expf(-opacity_logit[g]));
    const float L2E = 1.4426950408889634f;
    float A2 = -0.5f * L2E * dd * idet;
    float B2 =          L2E * b  * idet;
    float D2 = -0.5f * L2E * a  * idet;
    float L  = valid ? log2f(op) : -1e10f;

    float cr = 1.0f / (1.0f + expf(-color_pre[3*g+0]));
    float cg = 1.0f / (1.0f + expf(-color_pre[3*g+1]));
    float cl = 1.0f / (1.0f + expf(-color_pre[3*g+2]));

    float w6f = __uint_as_float(f32_bf16(cr) | (f32_bf16(cg) << 16));
    float w7f = __uint_as_float(f32_bf16(cl));

    // seg-th record float via cndmask chain (no runtime-indexed array)
    float lo = (seg < 2) ? ((seg == 0) ? m2dx : m2dy)
                         : ((seg == 2) ? A2   : B2);
    float hi = (seg < 6) ? ((seg == 4) ? D2   : L)
                         : ((seg == 6) ? w6f  : w7f);
    float rv = (seg < 4) ? lo : hi;

    // round-major slot: round = rank>>10, step = rank&15, lane = (rank>>4)&63
    int slot = (rank & ~1023) | ((rank & 15) << 6) | ((rank >> 4) & 63);
    srec[slot * RECF + seg] = rv;
}

// Scan-form compositing, TWO rounds of 1024 ranks, FOUR pixels per wave.
// Per round: 16 record loads (amortized over 4 px), colors kept in registers;
// wave prefix-product scan -> Tin; descending local pass (no loads);
// wave suffix scan -> S_out, M; fold into carries. Final single wave-reduce.
__global__ void __launch_bounds__(256)
gs_raster(const float* __restrict__ srec, float* __restrict__ out)
{
    int tid  = threadIdx.x;
    int lane = tid & 63;
    int wave = (blockIdx.x << 2) | (tid >> 6);    // 0..4095
    int p0   = wave * 4;                          // four pixels, same row
    float px0 = (float)(p0 & 127);
    float px1 = px0 + 1.0f, px2 = px0 + 2.0f, px3 = px0 + 3.0f;
    float py  = (float)(p0 >> 7);

    float G0=1.0f, G1=1.0f, G2=1.0f, G3=1.0f;         // prod(1-u)
    float Tc0=1.0f, Tc1=1.0f, Tc2=1.0f, Tc3=1.0f;     // prod(1-alpha)
    float Ar0=0.0f, Ag0=0.0f, Ab0=0.0f;               // deferred contribs
    float Ar1=0.0f, Ag1=0.0f, Ab1=0.0f;
    float Ar2=0.0f, Ag2=0.0f, Ab2=0.0f;
    float Ar3=0.0f, Ag3=0.0f, Ab3=0.0f;

    #pragma unroll 1
    for (int r = 0; r < 2; ++r) {
        const float* base = srec + (size_t)((r << 10) | lane) * RECF;

        // ---- pass 1: alphas + lane prefix products; keep colors ----
        float vA[16], vB[16], c6[16], c7[16];
        float P0=1.0f, P1=1.0f, P2=1.0f, P3=1.0f;
        #pragma unroll
        for (int i = 0; i < 16; ++i) {
            const float* rp = base + (size_t)(i << 6) * RECF;
            float4 ra = *(const float4*)rp;           // mux,muy,A2,B2
            float4 rb = *(const float4*)(rp + 4);     // D2,L,c6,c7
            c6[i] = rb.z;  c7[i] = rb.w;
            float dy   = py - ra.y;
            float b2dy = ra.w * dy;
            float t2   = fmaf(rb.x * dy, dy, rb.y);
            float dx0 = px0 - ra.x, dx1 = px1 - ra.x;
            float dx2 = px2 - ra.x, dx3 = px3 - ra.x;
            float q0 = fmaf(dx0, fmaf(ra.z, dx0, b2dy), t2);
            float q1 = fmaf(dx1, fmaf(ra.z, dx1, b2dy), t2);
            float q2 = fmaf(dx2, fmaf(ra.z, dx2, b2dy), t2);
            float q3 = fmaf(dx3, fmaf(ra.z, dx3, b2dy), t2);
            float a0 = fminf(__builtin_amdgcn_exp2f(q0), 0.99f);
            float a1 = fminf(__builtin_amdgcn_exp2f(q1), 0.99f);
            float a2 = fminf(__builtin_amdgcn_exp2f(q2), 0.99f);
            float a3 = fminf(__builtin_amdgcn_exp2f(q3), 0.99f);
            float u0 = P0 * a0;  P0 *= (1.0f - a0);
            float u1 = P1 * a1;  P1 *= (1.0f - a1);
            float u2 = P2 * a2;  P2 *= (1.0f - a2);
            float u3 = P3 * a3;  P3 *= (1.0f - a3);
            H2U hA; hA.h2 = __builtin_amdgcn_cvt_pkrtz(u0, u1);  vA[i] = hA.f;
            H2U hB; hB.h2 = __builtin_amdgcn_cvt_pkrtz(u2, u3);  vB[i] = hB.f;
        }

        // ---- wave inclusive prefix product of P -> Tin; round totals ----
        float sp0=P0, sp1=P1, sp2=P2, sp3=P3;
        #pragma unroll
        for (int d = 1; d < 64; d <<= 1) {
            float y0=__shfl_up(sp0,d), y1=__shfl_up(sp1,d);
            float y2=__shfl_up(sp2,d), y3=__shfl_up(sp3,d);
            if (lane >= d) { sp0*=y0; sp1*=y1; sp2*=y2; sp3*=y3; }
        }
        float e0=__shfl_up(sp0,1), e1=__shfl_up(sp1,1);
        float e2=__shfl_up(sp2,1), e3=__shfl_up(sp3,1);
        float Tin0 = Tc0 * ((lane==0)?1.0f:e0);
        float Tin1 = Tc1 * ((lane==0)?1.0f:e1);
        float Tin2 = Tc2 * ((lane==0)?1.0f:e2);
        float Tin3 = Tc3 * ((lane==0)?1.0f:e3);
        float tot0=__shfl(sp0,63), tot1=__shfl(sp1,63);
        float tot2=__shfl(sp2,63), tot3=__shfl(sp3,63);

        // ---- pass 2 (descending, register-only): contrib + B ----
        float Sl0=1.0f, Sl1=1.0f, Sl2=1.0f, Sl3=1.0f;
        float cr0=0,cg0=0,cb0=0, cr1=0,cg1=0,cb1=0;
        float cr2=0,cg2=0,cb2=0, cr3=0,cg3=0,cb3=0;
        #pragma unroll
        for (int i = 15; i >= 0; --i) {
            unsigned int w6 = __float_as_uint(c6[i]);
            unsigned int w7 = __float_as_uint(c7[i]);
            float ccr = __uint_as_float(w6 << 16);    // bf16 -> f32: 1 shl
            float ccg = __uint_as_float(w6 & 0xFFFF0000u);
            float ccb = __uint_as_float(w7 << 16);
            H2U hA; hA.f = vA[i];
            H2U hB; hB.f = vB[i];
            float u0 = Tin0 * (float)hA.h2.x;
            float us0 = u0 * Sl0;
            cr0 = fmaf(us0, ccr, cr0); cg0 = fmaf(us0, ccg, cg0); cb0 = fmaf(us0, ccb, cb0);
            Sl0 = fmaf(-u0, Sl0, Sl0);
            float u1 = Tin1 * (float)hA.h2.y;
            float us1 = u1 * Sl1;
            cr1 = fmaf(us1, ccr, cr1); cg1 = fmaf(us1, ccg, cg1); cb1 = fmaf(us1, ccb, cb1);
            Sl1 = fmaf(-u1, Sl1, Sl1);
            float u2 = Tin2 * (float)hB.h2.x;
            float us2 = u2 * Sl2;
            cr2 = fmaf(us2, ccr, cr2); cg2 = fmaf(us2, ccg, cg2); cb2 = fmaf(us2, ccb, cb2);
            Sl2 = fmaf(-u2, Sl2, Sl2);
            float u3 = Tin3 * (float)hB.h2.y;
            float us3 = u3 * Sl3;
            cr3 = fmaf(us3, ccr, cr3); cg3 = fmaf(us3, ccg, cg3); cb3 = fmaf(us3, ccb, cb3);
            Sl3 = fmaf(-u3, Sl3, Sl3);
        }

        // ---- wave inclusive suffix product of B -> S_out, M ----
        float ss0=Sl0, ss1=Sl1, ss2=Sl2, ss3=Sl3;
        #pragma unroll
        for (int d = 1; d < 64; d <<= 1) {
            float y0=__shfl_down(ss0,d), y1=__shfl_down(ss1,d);
            float y2=__shfl_down(ss2,d), y3=__shfl_down(ss3,d);
            if (lane + d < 64) { ss0*=y0; ss1*=y1; ss2*=y2; ss3*=y3; }
        }
        float f0=__shfl_down(ss0,1), f1=__shfl_down(ss1,1);
        float f2=__shfl_down(ss2,1), f3=__shfl_down(ss3,1);
        float So0 = (lane==63)?1.0f:f0;
        float So1 = (lane==63)?1.0f:f1;
        float So2 = (lane==63)?1.0f:f2;
        float So3 = (lane==63)?1.0f:f3;
        float M0=__shfl(ss0,0), M1=__shfl(ss1,0);
        float M2=__shfl(ss2,0), M3=__shfl(ss3,0);

        // ---- fold round into carries ----
        Ar0 = fmaf(Ar0, M0, cr0 * So0);
        Ag0 = fmaf(Ag0, M0, cg0 * So0);
        Ab0 = fmaf(Ab0, M0, cb0 * So0);
        Ar1 = fmaf(Ar1, M1, cr1 * So1);
        Ag1 = fmaf(Ag1, M1, cg1 * So1);
        Ab1 = fmaf(Ab1, M1, cb1 * So1);
        Ar2 = fmaf(Ar2, M2, cr2 * So2);
        Ag2 = fmaf(Ag2, M2, cg2 * So2);
        Ab2 = fmaf(Ab2, M2, cb2 * So2);
        Ar3 = fmaf(Ar3, M3, cr3 * So3);
        Ag3 = fmaf(Ag3, M3, cg3 * So3);
        Ab3 = fmaf(Ab3, M3, cb3 * So3);
        G0 *= M0;  G1 *= M1;  G2 *= M2;  G3 *= M3;
        Tc0 *= tot0;  Tc1 *= tot1;  Tc2 *= tot2;  Tc3 *= tot3;
    }

    // ---- wave sum-reduce the deferred contributions ----
    #pragma unroll
    for (int d = 1; d < 64; d <<= 1) {
        Ar0 += __shfl_xor(Ar0, d); Ag0 += __shfl_xor(Ag0, d); Ab0 += __shfl_xor(Ab0, d);
        Ar1 += __shfl_xor(Ar1, d); Ag1 += __shfl_xor(Ag1, d); Ab1 += __shfl_xor(Ab1, d);
        Ar2 += __shfl_xor(Ar2, d); Ag2 += __shfl_xor(Ag2, d); Ab2 += __shfl_xor(Ab2, d);
        Ar3 += __shfl_xor(Ar3, d); Ag3 += __shfl_xor(Ag3, d); Ab3 += __shfl_xor(Ab3, d);
    }

    if (lane == 0) {
        float* o0 = out + (size_t)p0 * 3;
        o0[0]  = fminf(fmaxf(G0 + Ar0, 0.0f), 1.0f);
        o0[1]  = fminf(fmaxf(G0 + Ag0, 0.0f), 1.0f);
        o0[2]  = fminf(fmaxf(G0 + Ab0, 0.0f), 1.0f);
        o0[3]  = fminf(fmaxf(G1 + Ar1, 0.0f), 1.0f);
        o0[4]  = fminf(fmaxf(G1 + Ag1, 0.0f), 1.0f);
        o0[5]  = fminf(fmaxf(G1 + Ab1, 0.0f), 1.0f);
        o0[6]  = fminf(fmaxf(G2 + Ar2, 0.0f), 1.0f);
        o0[7]  = fminf(fmaxf(G2 + Ag2, 0.0f), 1.0f);
        o0[8]  = fminf(fmaxf(G2 + Ab2, 0.0f), 1.0f);
        o0[9]  = fminf(fmaxf(G3 + Ar3, 0.0f), 1.0f);
        o0[10] = fminf(fmaxf(G3 + Ag3, 0.0f), 1.0f);
        o0[11] = fminf(fmaxf(G3 + Ab3, 0.0f), 1.0f);
    }
}

extern "C" void kernel_launch(void* const* d_in, const int* in_sizes, int n_in,
                              void* d_out, int out_size, void* d_ws, size_t ws_size,
                              hipStream_t stream)
{
    const float* means         = (const float*)d_in[0];
    const float* log_scales    = (const float*)d_in[1];
    const float* rotations     = (const float*)d_in[2];
    const float* opacity_logit = (const float*)d_in[3];
    const float* color_pre     = (const float*)d_in[4];
    const float* cam_pos       = (const float*)d_in[5];
    const float* look_at       = (const float*)d_in[6];
    float* out = (float*)d_out;

    float* srec = (float*)d_ws;                                      // 64 KB

    hipLaunchKernelGGL(gs_prep_rank, dim3(N_G / 32), dim3(256), 0, stream,
                       means, log_scales, rotations, opacity_logit, color_pre,
                       cam_pos, look_at, srec);
    // 16384 px / 4 px-per-wave = 4096 waves; 4 waves/block -> 1024 blocks
    hipLaunchKernelGGL(gs_raster, dim3(1024), dim3(256), 0, stream,
                       srec, out);
}